// Round 1
// baseline (442.712 us; speedup 1.0000x reference)
//
#include <hip/hip_runtime.h>

// MHA fused pipeline: B=4, S=2048, D=1024, H=16, HD=64.
//   k1: qkv = x @ w_qkv^T + b_qkv         (fp32 in -> bf16 out, ws)
//   k2: flash attention per (b,h), 64-row Q tiles, 64-row KV tiles
//   k3: out = vals @ w_o^T + b_o          (bf16 in -> fp32 out)

typedef __attribute__((ext_vector_type(4))) float f32x4;
typedef __attribute__((ext_vector_type(8))) short s16x8;
typedef __attribute__((ext_vector_type(4))) short s16x4;

__device__ __forceinline__ unsigned short f2bf(float f) {
  union { float f; unsigned u; } v; v.f = f;
  unsigned r = v.u + 0x7FFFu + ((v.u >> 16) & 1u);  // RNE
  return (unsigned short)(r >> 16);
}

// C[M,N] = A[M,K] @ Bw[N,K]^T + bias.  A fp32 or bf16(ushort), C fp32 or bf16.
template <bool A_F32, bool OUT_F32>
__global__ __launch_bounds__(256) void gemm_bt(
    const void* __restrict__ Aptr, const float* __restrict__ Bw,
    const float* __restrict__ bias, void* __restrict__ Cptr,
    int M, int N, int K) {
  __shared__ short lds_a[128][40];  // 32 K + 8 pad (80B row stride: 2-way bank, free)
  __shared__ short lds_b[128][40];
  const int t = threadIdx.x;
  const int l = t & 63;
  const int w = t >> 6;
  const int bm = blockIdx.y * 128;
  const int bn = blockIdx.x * 128;
  const int wr = (w >> 1) * 64;
  const int wc = (w & 1) * 64;
  const int lr = l & 15;
  const int lk = (l >> 4) * 8;

  f32x4 acc[4][4] = {};

  for (int k0 = 0; k0 < K; k0 += 32) {
    // ---- stage A tile (128 x 32) ----
    if (A_F32) {
      const float* A = (const float*)Aptr;
#pragma unroll
      for (int p = 0; p < 4; ++p) {
        const int row = (t >> 3) + p * 32;
        const int col = (t & 7) * 4;
        f32x4 v = *reinterpret_cast<const f32x4*>(&A[(size_t)(bm + row) * K + k0 + col]);
        s16x4 hv;
        hv.x = (short)f2bf(v.x); hv.y = (short)f2bf(v.y);
        hv.z = (short)f2bf(v.z); hv.w = (short)f2bf(v.w);
        *reinterpret_cast<s16x4*>(&lds_a[row][col]) = hv;
      }
    } else {
      const unsigned short* A = (const unsigned short*)Aptr;
#pragma unroll
      for (int p = 0; p < 2; ++p) {
        const int row = (t >> 2) + p * 64;
        const int col = (t & 3) * 8;
        s16x8 v = *reinterpret_cast<const s16x8*>(&A[(size_t)(bm + row) * K + k0 + col]);
        *reinterpret_cast<s16x8*>(&lds_a[row][col]) = v;
      }
    }
    // ---- stage B tile (128 x 32), weights always fp32 ----
#pragma unroll
    for (int p = 0; p < 4; ++p) {
      const int row = (t >> 3) + p * 32;
      const int col = (t & 7) * 4;
      f32x4 v = *reinterpret_cast<const f32x4*>(&Bw[(size_t)(bn + row) * K + k0 + col]);
      s16x4 hv;
      hv.x = (short)f2bf(v.x); hv.y = (short)f2bf(v.y);
      hv.z = (short)f2bf(v.z); hv.w = (short)f2bf(v.w);
      *reinterpret_cast<s16x4*>(&lds_b[row][col]) = hv;
    }
    __syncthreads();

    s16x8 af[4], bf[4];
#pragma unroll
    for (int mt = 0; mt < 4; ++mt)
      af[mt] = *reinterpret_cast<const s16x8*>(&lds_a[wr + mt * 16 + lr][lk]);
#pragma unroll
    for (int nt = 0; nt < 4; ++nt)
      bf[nt] = *reinterpret_cast<const s16x8*>(&lds_b[wc + nt * 16 + lr][lk]);
#pragma unroll
    for (int mt = 0; mt < 4; ++mt)
#pragma unroll
      for (int nt = 0; nt < 4; ++nt)
        acc[mt][nt] = __builtin_amdgcn_mfma_f32_16x16x32_bf16(af[mt], bf[nt], acc[mt][nt], 0, 0, 0);
    __syncthreads();
  }

  // epilogue: C row = (l>>4)*4+r, col = l&15  (verified C/D layout)
#pragma unroll
  for (int mt = 0; mt < 4; ++mt) {
#pragma unroll
    for (int nt = 0; nt < 4; ++nt) {
#pragma unroll
      for (int r = 0; r < 4; ++r) {
        const int row = bm + wr + mt * 16 + (l >> 4) * 4 + r;
        const int col = bn + wc + nt * 16 + lr;
        const float vv = acc[mt][nt][r] + bias[col];
        if (OUT_F32)
          ((float*)Cptr)[(size_t)row * N + col] = vv;
        else
          ((unsigned short*)Cptr)[(size_t)row * N + col] = f2bf(vv);
      }
    }
  }
}

// Flash attention. qkv[bs][3072] bf16, head h: q at h*192, k at +64, v at +128.
// Block: (q-tile of 64 rows) x (b,h). 4 waves, wave w owns Q rows w*16..w*16+16.
__global__ __launch_bounds__(256) void attn_kernel(
    const unsigned short* __restrict__ qkv, unsigned short* __restrict__ vals) {
  __shared__ short q_lds[64][80];   // +16 pad: 160B stride, 16B-aligned b128 reads
  __shared__ short k_lds[64][80];
  __shared__ short vt_lds[64][80];  // V transposed: vt[d][kv]
  __shared__ short p_lds[64][80];
  const int t = threadIdx.x;
  const int l = t & 63;
  const int w = t >> 6;
  const int lr = l & 15;
  const int lkh = l >> 4;
  const int qt = blockIdx.x;
  const int bh = blockIdx.y;
  const int b = bh >> 4;
  const int h = bh & 15;
  const size_t rowbase = (size_t)b * 2048;
  const int qcol = h * 192;

  // stage Q tile once
#pragma unroll
  for (int p = 0; p < 2; ++p) {
    const int row = (t >> 3) + p * 32;
    const int col = (t & 7) * 8;
    s16x8 v = *reinterpret_cast<const s16x8*>(
        &qkv[(rowbase + qt * 64 + row) * 3072 + qcol + col]);
    *reinterpret_cast<s16x8*>(&q_lds[row][col]) = v;
  }

  f32x4 o_acc[4] = {};
  float m_r[4] = {-1e30f, -1e30f, -1e30f, -1e30f};
  float l_r[4] = {0.f, 0.f, 0.f, 0.f};

  for (int kt = 0; kt < 32; ++kt) {
    __syncthreads();  // previous iter done reading k/vt (and Q visible at kt=0)
    // stage K (row-major) and V (transposed)
#pragma unroll
    for (int p = 0; p < 2; ++p) {
      const int row = (t >> 3) + p * 32;
      const int col = (t & 7) * 8;
      const size_t g = (rowbase + (size_t)kt * 64 + row) * 3072 + qcol;
      s16x8 kv = *reinterpret_cast<const s16x8*>(&qkv[g + 64 + col]);
      *reinterpret_cast<s16x8*>(&k_lds[row][col]) = kv;
      s16x8 vv = *reinterpret_cast<const s16x8*>(&qkv[g + 128 + col]);
#pragma unroll
      for (int j = 0; j < 8; ++j) vt_lds[col + j][row] = vv[j];
    }
    __syncthreads();

    // S = Q K^T (16 rows x 64 cols per wave)
    f32x4 s_acc[4] = {};
    s16x8 qf0 = *reinterpret_cast<const s16x8*>(&q_lds[w * 16 + lr][lkh * 8]);
    s16x8 qf1 = *reinterpret_cast<const s16x8*>(&q_lds[w * 16 + lr][32 + lkh * 8]);
#pragma unroll
    for (int nt = 0; nt < 4; ++nt) {
      s16x8 kf0 = *reinterpret_cast<const s16x8*>(&k_lds[nt * 16 + lr][lkh * 8]);
      s16x8 kf1 = *reinterpret_cast<const s16x8*>(&k_lds[nt * 16 + lr][32 + lkh * 8]);
      s_acc[nt] = __builtin_amdgcn_mfma_f32_16x16x32_bf16(qf0, kf0, s_acc[nt], 0, 0, 0);
      s_acc[nt] = __builtin_amdgcn_mfma_f32_16x16x32_bf16(qf1, kf1, s_acc[nt], 0, 0, 0);
    }

    // online softmax; lane holds rows lkh*4+r at cols nt*16+lr
#pragma unroll
    for (int r = 0; r < 4; ++r) {
      float s0 = s_acc[0][r] * 0.125f;
      float s1 = s_acc[1][r] * 0.125f;
      float s2 = s_acc[2][r] * 0.125f;
      float s3 = s_acc[3][r] * 0.125f;
      float mx = fmaxf(fmaxf(s0, s1), fmaxf(s2, s3));
#pragma unroll
      for (int mm = 1; mm <= 8; mm <<= 1) mx = fmaxf(mx, __shfl_xor(mx, mm));
      const float mnew = fmaxf(m_r[r], mx);
      const float sc = __expf(m_r[r] - mnew);
      m_r[r] = mnew;
      const float p0 = __expf(s0 - mnew);
      const float p1 = __expf(s1 - mnew);
      const float p2 = __expf(s2 - mnew);
      const float p3 = __expf(s3 - mnew);
      float rs = p0 + p1 + p2 + p3;
#pragma unroll
      for (int mm = 1; mm <= 8; mm <<= 1) rs += __shfl_xor(rs, mm);
      l_r[r] = l_r[r] * sc + rs;
      o_acc[0][r] *= sc; o_acc[1][r] *= sc; o_acc[2][r] *= sc; o_acc[3][r] *= sc;
      p_lds[w * 16 + lkh * 4 + r][lr]      = (short)f2bf(p0);
      p_lds[w * 16 + lkh * 4 + r][16 + lr] = (short)f2bf(p1);
      p_lds[w * 16 + lkh * 4 + r][32 + lr] = (short)f2bf(p2);
      p_lds[w * 16 + lkh * 4 + r][48 + lr] = (short)f2bf(p3);
    }
    __syncthreads();  // P visible (wave-local, but be safe)

    // O += P @ V
#pragma unroll
    for (int kk = 0; kk < 2; ++kk) {
      s16x8 pf = *reinterpret_cast<const s16x8*>(&p_lds[w * 16 + lr][kk * 32 + lkh * 8]);
#pragma unroll
      for (int nt = 0; nt < 4; ++nt) {
        s16x8 vf = *reinterpret_cast<const s16x8*>(&vt_lds[nt * 16 + lr][kk * 32 + lkh * 8]);
        o_acc[nt] = __builtin_amdgcn_mfma_f32_16x16x32_bf16(pf, vf, o_acc[nt], 0, 0, 0);
      }
    }
  }

  // epilogue: vals[b*2048+s][h*64+d] bf16
#pragma unroll
  for (int r = 0; r < 4; ++r) {
    const float inv = 1.0f / l_r[r];
    const size_t row = rowbase + qt * 64 + w * 16 + lkh * 4 + r;
#pragma unroll
    for (int nt = 0; nt < 4; ++nt) {
      vals[row * 1024 + h * 64 + nt * 16 + lr] = f2bf(o_acc[nt][r] * inv);
    }
  }
}

extern "C" void kernel_launch(void* const* d_in, const int* in_sizes, int n_in,
                              void* d_out, int out_size, void* d_ws, size_t ws_size,
                              hipStream_t stream) {
  const float* x     = (const float*)d_in[0];   // [4,2048,1024]
  const float* w_qkv = (const float*)d_in[1];   // [3072,1024]
  const float* b_qkv = (const float*)d_in[2];   // [3072]
  const float* w_o   = (const float*)d_in[3];   // [1024,1024]
  const float* b_o   = (const float*)d_in[4];   // [1024]
  float* out = (float*)d_out;                   // [4,2048,1024] fp32

  unsigned short* qkv_ws  = (unsigned short*)d_ws;                 // 8192x3072 bf16
  unsigned short* vals_ws = qkv_ws + (size_t)8192 * 3072;          // 8192x1024 bf16

  // 1) qkv projection
  gemm_bt<true, false><<<dim3(3072 / 128, 8192 / 128), 256, 0, stream>>>(
      x, w_qkv, b_qkv, qkv_ws, 8192, 3072, 1024);
  // 2) attention
  attn_kernel<<<dim3(2048 / 64, 64), 256, 0, stream>>>(qkv_ws, vals_ws);
  // 3) output projection
  gemm_bt<false, true><<<dim3(1024 / 128, 8192 / 128), 256, 0, stream>>>(
      vals_ws, w_o, b_o, out, 8192, 1024, 1024);
}

// Round 2
// 400.689 us; speedup vs baseline: 1.1049x; 1.1049x over previous
//
#include <hip/hip_runtime.h>

// MHA fused pipeline: B=4, S=2048, D=1024, H=16, HD=64.
//   k1: qkv = x @ w_qkv^T + b_qkv         (fp32 in -> bf16 out, ws)
//   k2: flash attention per (b,h), 64-row Q tiles, 64-row KV tiles
//   k3: out = vals @ w_o^T + b_o          (bf16 in -> fp32 out)

typedef __attribute__((ext_vector_type(4))) float f32x4;
typedef __attribute__((ext_vector_type(8))) short s16x8;
typedef __attribute__((ext_vector_type(4))) short s16x4;

__device__ __forceinline__ unsigned short f2bf(float f) {
  union { float f; unsigned u; } v; v.f = f;
  unsigned r = v.u + 0x7FFFu + ((v.u >> 16) & 1u);  // RNE
  return (unsigned short)(r >> 16);
}
__device__ __forceinline__ float bf2f(unsigned short u) {
  union { unsigned u; float f; } v; v.u = ((unsigned)u) << 16;
  return v.f;
}

// C[M,N] = A[M,K] @ Bw[N,K]^T + bias.  A fp32 or bf16(ushort), C fp32 or bf16.
template <bool A_F32, bool OUT_F32>
__global__ __launch_bounds__(256) void gemm_bt(
    const void* __restrict__ Aptr, const float* __restrict__ Bw,
    const float* __restrict__ bias, void* __restrict__ Cptr,
    int M, int N, int K) {
  __shared__ short lds_a[128][40];
  __shared__ short lds_b[128][40];
  const int t = threadIdx.x;
  const int l = t & 63;
  const int w = t >> 6;
  const int bm = blockIdx.y * 128;
  const int bn = blockIdx.x * 128;
  const int wr = (w >> 1) * 64;
  const int wc = (w & 1) * 64;
  const int lr = l & 15;
  const int lk = (l >> 4) * 8;

  f32x4 acc[4][4] = {};

  for (int k0 = 0; k0 < K; k0 += 32) {
    if (A_F32) {
      const float* A = (const float*)Aptr;
#pragma unroll
      for (int p = 0; p < 4; ++p) {
        const int row = (t >> 3) + p * 32;
        const int col = (t & 7) * 4;
        f32x4 v = *reinterpret_cast<const f32x4*>(&A[(size_t)(bm + row) * K + k0 + col]);
        s16x4 hv;
        hv.x = (short)f2bf(v.x); hv.y = (short)f2bf(v.y);
        hv.z = (short)f2bf(v.z); hv.w = (short)f2bf(v.w);
        *reinterpret_cast<s16x4*>(&lds_a[row][col]) = hv;
      }
    } else {
      const unsigned short* A = (const unsigned short*)Aptr;
#pragma unroll
      for (int p = 0; p < 2; ++p) {
        const int row = (t >> 2) + p * 64;
        const int col = (t & 3) * 8;
        s16x8 v = *reinterpret_cast<const s16x8*>(&A[(size_t)(bm + row) * K + k0 + col]);
        *reinterpret_cast<s16x8*>(&lds_a[row][col]) = v;
      }
    }
#pragma unroll
    for (int p = 0; p < 4; ++p) {
      const int row = (t >> 3) + p * 32;
      const int col = (t & 7) * 4;
      f32x4 v = *reinterpret_cast<const f32x4*>(&Bw[(size_t)(bn + row) * K + k0 + col]);
      s16x4 hv;
      hv.x = (short)f2bf(v.x); hv.y = (short)f2bf(v.y);
      hv.z = (short)f2bf(v.z); hv.w = (short)f2bf(v.w);
      *reinterpret_cast<s16x4*>(&lds_b[row][col]) = hv;
    }
    __syncthreads();

    s16x8 af[4], bfr[4];
#pragma unroll
    for (int mt = 0; mt < 4; ++mt)
      af[mt] = *reinterpret_cast<const s16x8*>(&lds_a[wr + mt * 16 + lr][lk]);
#pragma unroll
    for (int nt = 0; nt < 4; ++nt)
      bfr[nt] = *reinterpret_cast<const s16x8*>(&lds_b[wc + nt * 16 + lr][lk]);
#pragma unroll
    for (int mt = 0; mt < 4; ++mt)
#pragma unroll
      for (int nt = 0; nt < 4; ++nt)
        acc[mt][nt] = __builtin_amdgcn_mfma_f32_16x16x32_bf16(af[mt], bfr[nt], acc[mt][nt], 0, 0, 0);
    __syncthreads();
  }

#pragma unroll
  for (int mt = 0; mt < 4; ++mt) {
#pragma unroll
    for (int nt = 0; nt < 4; ++nt) {
#pragma unroll
      for (int r = 0; r < 4; ++r) {
        const int row = bm + wr + mt * 16 + (l >> 4) * 4 + r;
        const int col = bn + wc + nt * 16 + lr;
        const float vv = acc[mt][nt][r] + bias[col];
        if (OUT_F32)
          ((float*)Cptr)[(size_t)row * N + col] = vv;
        else
          ((unsigned short*)Cptr)[(size_t)row * N + col] = f2bf(vv);
      }
    }
  }
}

// Flash attention. qkv[bs][3072] bf16, head h: q at h*192, k at +64, v at +128.
// 4 waves; wave w owns Q rows w*16..w*16+15 of a 64-row Q tile. KV tile = 64.
// K/VT double-buffered [64][72] (144B stride: bank step 4, period 8 => all
// b128 LDS ops at 8-phase minimum). V transposed on the GLOBAL side: lane=d
// column loads (coalesced 128B/instr) + one b128 LDS write per 8 kv.
__global__ __launch_bounds__(256) void attn_kernel(
    const unsigned short* __restrict__ qkv, unsigned short* __restrict__ vals) {
  __shared__ short k_lds[2][64][72];
  __shared__ short vt_lds[2][64][72];  // vt[d][kv]
  __shared__ short p_lds[64][72];      // also Q staging at init
  const int t = threadIdx.x;
  const int l = t & 63;
  const int w = t >> 6;
  const int lr = l & 15;
  const int lkh = l >> 4;
  const int qt = blockIdx.x;
  const int bh = blockIdx.y;
  const int b = bh >> 4;
  const int h = bh & 15;
  const size_t rowbase = (size_t)b * 2048;
  const int qcol = h * 192;
  const int kcol = qcol + 64;
  const int vcol = qcol + 128;

  // ---- stage Q (scaled by 1/sqrt(64)*log2e, softmax runs in exp2 domain) ----
  const float qscale = 0.125f * 1.44269504f;
#pragma unroll
  for (int p = 0; p < 2; ++p) {
    const int row = (t >> 3) + p * 32;
    const int col = (t & 7) * 8;
    s16x8 v = *reinterpret_cast<const s16x8*>(
        &qkv[(rowbase + qt * 64 + row) * 3072 + qcol + col]);
    s16x8 sv;
#pragma unroll
    for (int j = 0; j < 8; ++j)
      sv[j] = (short)f2bf(bf2f((unsigned short)v[j]) * qscale);
    *reinterpret_cast<s16x8*>(&p_lds[row][col]) = sv;
  }
  // ---- stage K/V tile 0 directly into buffer 0 ----
#pragma unroll
  for (int p = 0; p < 2; ++p) {
    const int row = (t >> 3) + p * 32;
    const int col = (t & 7) * 8;
    s16x8 kv8 = *reinterpret_cast<const s16x8*>(
        &qkv[(rowbase + row) * 3072 + kcol + col]);
    *reinterpret_cast<s16x8*>(&k_lds[0][row][col]) = kv8;
  }
#pragma unroll
  for (int p = 0; p < 2; ++p) {
    const int kv0 = p * 32 + w * 8;
    s16x8 pv;
#pragma unroll
    for (int j = 0; j < 8; ++j)
      pv[j] = (short)qkv[(rowbase + kv0 + j) * 3072 + vcol + l];
    *reinterpret_cast<s16x8*>(&vt_lds[0][l][kv0]) = pv;
  }
  __syncthreads();

  // Q fragments -> registers; p_lds is reused for P from here (wave-local rows)
  s16x8 qf0 = *reinterpret_cast<const s16x8*>(&p_lds[w * 16 + lr][lkh * 8]);
  s16x8 qf1 = *reinterpret_cast<const s16x8*>(&p_lds[w * 16 + lr][32 + lkh * 8]);

  f32x4 o_acc[4] = {};
  float m_r[4] = {-1e30f, -1e30f, -1e30f, -1e30f};
  float l_r[4] = {0.f, 0.f, 0.f, 0.f};

  for (int kt = 0; kt < 32; ++kt) {
    const int cur = kt & 1;
    const int nxt = cur ^ 1;
    const bool pre = (kt + 1) < 32;

    // ---- issue next-tile global loads early (latency hides under compute) ----
    s16x8 kreg0, kreg1;
    s16x8 vreg0, vreg1;
    if (pre) {
      const size_t base = rowbase + (size_t)(kt + 1) * 64;
      {
        const int row = (t >> 3);
        const int col = (t & 7) * 8;
        kreg0 = *reinterpret_cast<const s16x8*>(&qkv[(base + row) * 3072 + kcol + col]);
        kreg1 = *reinterpret_cast<const s16x8*>(&qkv[(base + row + 32) * 3072 + kcol + col]);
      }
      const int kv0 = w * 8;
#pragma unroll
      for (int j = 0; j < 8; ++j)
        vreg0[j] = (short)qkv[(base + kv0 + j) * 3072 + vcol + l];
#pragma unroll
      for (int j = 0; j < 8; ++j)
        vreg1[j] = (short)qkv[(base + 32 + kv0 + j) * 3072 + vcol + l];
    }

    // ---- S = Q K^T ----
    f32x4 s_acc[4] = {};
#pragma unroll
    for (int nt = 0; nt < 4; ++nt) {
      s16x8 kf0 = *reinterpret_cast<const s16x8*>(&k_lds[cur][nt * 16 + lr][lkh * 8]);
      s16x8 kf1 = *reinterpret_cast<const s16x8*>(&k_lds[cur][nt * 16 + lr][32 + lkh * 8]);
      s_acc[nt] = __builtin_amdgcn_mfma_f32_16x16x32_bf16(qf0, kf0, s_acc[nt], 0, 0, 0);
      s_acc[nt] = __builtin_amdgcn_mfma_f32_16x16x32_bf16(qf1, kf1, s_acc[nt], 0, 0, 0);
    }

    // ---- online softmax (exp2 domain); lane: rows lkh*4+r, cols nt*16+lr ----
#pragma unroll
    for (int r = 0; r < 4; ++r) {
      float s0 = s_acc[0][r], s1 = s_acc[1][r], s2 = s_acc[2][r], s3 = s_acc[3][r];
      float mx = fmaxf(fmaxf(s0, s1), fmaxf(s2, s3));
#pragma unroll
      for (int mm = 1; mm <= 8; mm <<= 1) mx = fmaxf(mx, __shfl_xor(mx, mm));
      const float mnew = fmaxf(m_r[r], mx);
      const float sc = exp2f(m_r[r] - mnew);
      m_r[r] = mnew;
      const float p0 = exp2f(s0 - mnew);
      const float p1 = exp2f(s1 - mnew);
      const float p2 = exp2f(s2 - mnew);
      const float p3 = exp2f(s3 - mnew);
      float rs = p0 + p1 + p2 + p3;
#pragma unroll
      for (int mm = 1; mm <= 8; mm <<= 1) rs += __shfl_xor(rs, mm);
      l_r[r] = l_r[r] * sc + rs;
      o_acc[0][r] *= sc; o_acc[1][r] *= sc; o_acc[2][r] *= sc; o_acc[3][r] *= sc;
      const int prow = w * 16 + lkh * 4 + r;
      p_lds[prow][lr]      = (short)f2bf(p0);
      p_lds[prow][16 + lr] = (short)f2bf(p1);
      p_lds[prow][32 + lr] = (short)f2bf(p2);
      p_lds[prow][48 + lr] = (short)f2bf(p3);
    }

    // ---- O += P @ V ----
#pragma unroll
    for (int kk = 0; kk < 2; ++kk) {
      s16x8 pf = *reinterpret_cast<const s16x8*>(&p_lds[w * 16 + lr][kk * 32 + lkh * 8]);
#pragma unroll
      for (int nt = 0; nt < 4; ++nt) {
        s16x8 vf = *reinterpret_cast<const s16x8*>(&vt_lds[cur][nt * 16 + lr][kk * 32 + lkh * 8]);
        o_acc[nt] = __builtin_amdgcn_mfma_f32_16x16x32_bf16(pf, vf, o_acc[nt], 0, 0, 0);
      }
    }

    // ---- write staged regs into the other buffer ----
    if (pre) {
      const int row = (t >> 3);
      const int col = (t & 7) * 8;
      *reinterpret_cast<s16x8*>(&k_lds[nxt][row][col]) = kreg0;
      *reinterpret_cast<s16x8*>(&k_lds[nxt][row + 32][col]) = kreg1;
      const int kv0 = w * 8;
      *reinterpret_cast<s16x8*>(&vt_lds[nxt][l][kv0]) = vreg0;
      *reinterpret_cast<s16x8*>(&vt_lds[nxt][l][32 + kv0]) = vreg1;
    }
    __syncthreads();
  }

  // ---- epilogue: vals[b*2048+s][h*64+d] bf16 ----
#pragma unroll
  for (int r = 0; r < 4; ++r) {
    const float inv = 1.0f / l_r[r];
    const size_t row = rowbase + qt * 64 + w * 16 + lkh * 4 + r;
#pragma unroll
    for (int nt = 0; nt < 4; ++nt) {
      vals[row * 1024 + h * 64 + nt * 16 + lr] = f2bf(o_acc[nt][r] * inv);
    }
  }
}

extern "C" void kernel_launch(void* const* d_in, const int* in_sizes, int n_in,
                              void* d_out, int out_size, void* d_ws, size_t ws_size,
                              hipStream_t stream) {
  const float* x     = (const float*)d_in[0];   // [4,2048,1024]
  const float* w_qkv = (const float*)d_in[1];   // [3072,1024]
  const float* b_qkv = (const float*)d_in[2];   // [3072]
  const float* w_o   = (const float*)d_in[3];   // [1024,1024]
  const float* b_o   = (const float*)d_in[4];   // [1024]
  float* out = (float*)d_out;                   // [4,2048,1024] fp32

  unsigned short* qkv_ws  = (unsigned short*)d_ws;                 // 8192x3072 bf16
  unsigned short* vals_ws = qkv_ws + (size_t)8192 * 3072;          // 8192x1024 bf16

  gemm_bt<true, false><<<dim3(3072 / 128, 8192 / 128), 256, 0, stream>>>(
      x, w_qkv, b_qkv, qkv_ws, 8192, 3072, 1024);
  attn_kernel<<<dim3(2048 / 64, 64), 256, 0, stream>>>(qkv_ws, vals_ws);
  gemm_bt<false, true><<<dim3(1024 / 128, 8192 / 128), 256, 0, stream>>>(
      vals_ws, w_o, b_o, out, 8192, 1024, 1024);
}

// Round 4
// 302.160 us; speedup vs baseline: 1.4652x; 1.3261x over previous
//
#include <hip/hip_runtime.h>
#include <hip/hip_bf16.h>

// MHA fused pipeline: B=4, S=2048, D=1024, H=16, HD=64.
//   k1: qkv = x @ w_qkv^T + b_qkv         (fp32 in -> bf16 out, ws)
//   k2: flash attention, swapped-QK^T lane-local softmax, defer-max
//   k3: out = vals @ w_o^T + b_o          (bf16 in -> fp32 out)

typedef __attribute__((ext_vector_type(4))) float f32x4;
typedef __attribute__((ext_vector_type(8))) short s16x8;
typedef __attribute__((ext_vector_type(4))) short s16x4;
typedef __attribute__((ext_vector_type(2))) unsigned u32x2;
typedef __attribute__((ext_vector_type(4))) unsigned u32x4;

__device__ __forceinline__ unsigned short f2bf(float f) {
  __hip_bfloat16 h = __float2bfloat16(f);
  unsigned short u;
  __builtin_memcpy(&u, &h, 2);
  return u;
}
__device__ __forceinline__ unsigned pack2bf(float a, float b) {
  return (unsigned)f2bf(a) | ((unsigned)f2bf(b) << 16);
}
__device__ __forceinline__ float bf2f(unsigned short u) {
  union { unsigned u; float f; } v; v.u = ((unsigned)u) << 16;
  return v.f;
}

// C[M,N] = A[M,K] @ Bw[N,K]^T + bias.  A fp32 or bf16(ushort), C fp32 or bf16.
template <bool A_F32, bool OUT_F32>
__global__ __launch_bounds__(256) void gemm_bt(
    const void* __restrict__ Aptr, const float* __restrict__ Bw,
    const float* __restrict__ bias, void* __restrict__ Cptr,
    int M, int N, int K) {
  __shared__ short lds_a[128][40];
  __shared__ short lds_b[128][40];
  const int t = threadIdx.x;
  const int l = t & 63;
  const int w = t >> 6;
  const int bm = blockIdx.y * 128;
  const int bn = blockIdx.x * 128;
  const int wr = (w >> 1) * 64;
  const int wc = (w & 1) * 64;
  const int lr = l & 15;
  const int lk = (l >> 4) * 8;

  f32x4 acc[4][4] = {};

  for (int k0 = 0; k0 < K; k0 += 32) {
    if (A_F32) {
      const float* A = (const float*)Aptr;
#pragma unroll
      for (int p = 0; p < 4; ++p) {
        const int row = (t >> 3) + p * 32;
        const int col = (t & 7) * 4;
        f32x4 v = *reinterpret_cast<const f32x4*>(&A[(size_t)(bm + row) * K + k0 + col]);
        u32x2 pk;
        pk.x = pack2bf(v.x, v.y);
        pk.y = pack2bf(v.z, v.w);
        *reinterpret_cast<u32x2*>(&lds_a[row][col]) = pk;
      }
    } else {
      const unsigned short* A = (const unsigned short*)Aptr;
#pragma unroll
      for (int p = 0; p < 2; ++p) {
        const int row = (t >> 2) + p * 64;
        const int col = (t & 3) * 8;
        s16x8 v = *reinterpret_cast<const s16x8*>(&A[(size_t)(bm + row) * K + k0 + col]);
        *reinterpret_cast<s16x8*>(&lds_a[row][col]) = v;
      }
    }
#pragma unroll
    for (int p = 0; p < 4; ++p) {
      const int row = (t >> 3) + p * 32;
      const int col = (t & 7) * 4;
      f32x4 v = *reinterpret_cast<const f32x4*>(&Bw[(size_t)(bn + row) * K + k0 + col]);
      u32x2 pk;
      pk.x = pack2bf(v.x, v.y);
      pk.y = pack2bf(v.z, v.w);
      *reinterpret_cast<u32x2*>(&lds_b[row][col]) = pk;
    }
    __syncthreads();

    s16x8 af[4], bfr[4];
#pragma unroll
    for (int mt = 0; mt < 4; ++mt)
      af[mt] = *reinterpret_cast<const s16x8*>(&lds_a[wr + mt * 16 + lr][lk]);
#pragma unroll
    for (int nt = 0; nt < 4; ++nt)
      bfr[nt] = *reinterpret_cast<const s16x8*>(&lds_b[wc + nt * 16 + lr][lk]);
#pragma unroll
    for (int mt = 0; mt < 4; ++mt)
#pragma unroll
      for (int nt = 0; nt < 4; ++nt)
        acc[mt][nt] = __builtin_amdgcn_mfma_f32_16x16x32_bf16(af[mt], bfr[nt], acc[mt][nt], 0, 0, 0);
    __syncthreads();
  }

#pragma unroll
  for (int mt = 0; mt < 4; ++mt) {
#pragma unroll
    for (int nt = 0; nt < 4; ++nt) {
#pragma unroll
      for (int r = 0; r < 4; ++r) {
        const int row = bm + wr + mt * 16 + (l >> 4) * 4 + r;
        const int col = bn + wc + nt * 16 + lr;
        const float vv = acc[mt][nt][r] + bias[col];
        if (OUT_F32)
          ((float*)Cptr)[(size_t)row * N + col] = vv;
        else
          ((unsigned short*)Cptr)[(size_t)row * N + col] = f2bf(vv);
      }
    }
  }
}

// Flash attention. qkv[bs][3072] bf16, head h: q at h*192, k at +64, v at +128.
// Swapped QK^T: s_acc = mfma(K, Q) -> S^T[kv][q=lr]; softmax reduction is
// 16 in-lane values + shfl_xor(16,32). Defer-max rescale (THR=8, exp2 domain).
// K single-buffered (mid-loop barrier), V^T double-buffered. LDS 36 KB -> 4 blk/CU.
__global__ __launch_bounds__(256, 4) void attn_kernel(
    const unsigned short* __restrict__ qkv, unsigned short* __restrict__ vals) {
  __shared__ short k_lds[64][72];
  __shared__ short vt_lds[2][64][72];  // vt[d][kv]
  __shared__ short p_lds[64][72];      // Q staging at init, then P[q][kv]
  const int t = threadIdx.x;
  const int l = t & 63;
  const int w = t >> 6;
  const int lr = l & 15;
  const int lkh = l >> 4;
  const int qt = blockIdx.x;
  const int bh = blockIdx.y;
  const int b = bh >> 4;
  const int h = bh & 15;
  const size_t rowbase = (size_t)b * 2048;
  const int qcol = h * 192;
  const int kcol = qcol + 64;
  const int vcol = qcol + 128;

  // ---- stage Q (scaled by 1/8 * log2e; softmax runs in exp2 domain) ----
  const float qscale = 0.125f * 1.44269504f;
#pragma unroll
  for (int p = 0; p < 2; ++p) {
    const int row = (t >> 3) + p * 32;
    const int col = (t & 7) * 8;
    s16x8 v = *reinterpret_cast<const s16x8*>(
        &qkv[(rowbase + qt * 64 + row) * 3072 + qcol + col]);
    u32x4 q4;
    q4.x = pack2bf(bf2f((unsigned short)v[0]) * qscale, bf2f((unsigned short)v[1]) * qscale);
    q4.y = pack2bf(bf2f((unsigned short)v[2]) * qscale, bf2f((unsigned short)v[3]) * qscale);
    q4.z = pack2bf(bf2f((unsigned short)v[4]) * qscale, bf2f((unsigned short)v[5]) * qscale);
    q4.w = pack2bf(bf2f((unsigned short)v[6]) * qscale, bf2f((unsigned short)v[7]) * qscale);
    *reinterpret_cast<u32x4*>(&p_lds[row][col]) = q4;
  }
  // ---- stage K tile 0 / V^T tile 0 ----
#pragma unroll
  for (int p = 0; p < 2; ++p) {
    const int row = (t >> 3) + p * 32;
    const int col = (t & 7) * 8;
    s16x8 kv8 = *reinterpret_cast<const s16x8*>(&qkv[(rowbase + row) * 3072 + kcol + col]);
    *reinterpret_cast<s16x8*>(&k_lds[row][col]) = kv8;
  }
#pragma unroll
  for (int p = 0; p < 2; ++p) {
    const int kv0 = p * 32 + w * 8;
    s16x8 vv;
#pragma unroll
    for (int j = 0; j < 8; ++j)
      vv[j] = (short)qkv[(rowbase + kv0 + j) * 3072 + vcol + l];
    *reinterpret_cast<s16x8*>(&vt_lds[0][l][kv0]) = vv;
  }
  __syncthreads();

  // Q fragments -> registers (B-operand layout == A layout); p_lds reused for P
  s16x8 qf0 = *reinterpret_cast<const s16x8*>(&p_lds[w * 16 + lr][lkh * 8]);
  s16x8 qf1 = *reinterpret_cast<const s16x8*>(&p_lds[w * 16 + lr][32 + lkh * 8]);

  f32x4 o_acc[4] = {};
  float m_s = -1e30f;
  float l_s = 0.f;

  for (int kt = 0; kt < 32; ++kt) {
    const int cur = kt & 1;
    const int nxt = cur ^ 1;
    const bool pre = (kt + 1) < 32;

    // ---- issue next K loads early (drained by the mid-loop barrier anyway) ----
    s16x8 kreg0, kreg1;
    const size_t nbase = rowbase + (size_t)(kt + 1) * 64;
    if (pre) {
      const int row = (t >> 3);
      const int col = (t & 7) * 8;
      kreg0 = *reinterpret_cast<const s16x8*>(&qkv[(nbase + row) * 3072 + kcol + col]);
      kreg1 = *reinterpret_cast<const s16x8*>(&qkv[(nbase + row + 32) * 3072 + kcol + col]);
    }

    // ---- S^T = K Q^T (swapped operands) ----
    f32x4 s_acc[4] = {};
#pragma unroll
    for (int nt = 0; nt < 4; ++nt) {
      s16x8 kf0 = *reinterpret_cast<const s16x8*>(&k_lds[nt * 16 + lr][lkh * 8]);
      s16x8 kf1 = *reinterpret_cast<const s16x8*>(&k_lds[nt * 16 + lr][32 + lkh * 8]);
      s_acc[nt] = __builtin_amdgcn_mfma_f32_16x16x32_bf16(kf0, qf0, s_acc[nt], 0, 0, 0);
      s_acc[nt] = __builtin_amdgcn_mfma_f32_16x16x32_bf16(kf1, qf1, s_acc[nt], 0, 0, 0);
    }
    __syncthreads();  // all waves done reading k_lds

    // ---- write next K tile (kreg needed now; vmcnt drain is cheap) ----
    if (pre) {
      const int row = (t >> 3);
      const int col = (t & 7) * 8;
      *reinterpret_cast<s16x8*>(&k_lds[row][col]) = kreg0;
      *reinterpret_cast<s16x8*>(&k_lds[row + 32][col]) = kreg1;
    }

    // ---- issue next V loads (latency hides under softmax + PV) ----
    s16x8 vreg0, vreg1;
    if (pre) {
      const int kv0 = w * 8;
#pragma unroll
      for (int j = 0; j < 8; ++j)
        vreg0[j] = (short)qkv[(nbase + kv0 + j) * 3072 + vcol + l];
#pragma unroll
      for (int j = 0; j < 8; ++j)
        vreg1[j] = (short)qkv[(nbase + 32 + kv0 + j) * 3072 + vcol + l];
    }

    // ---- softmax: lane holds S^T[kv = nt*16+lkh*4+r][q = lr] ----
    float mx = -1e30f;
#pragma unroll
    for (int nt = 0; nt < 4; ++nt)
      mx = fmaxf(mx, fmaxf(fmaxf(s_acc[nt][0], s_acc[nt][1]),
                           fmaxf(s_acc[nt][2], s_acc[nt][3])));
    mx = fmaxf(mx, __shfl_xor(mx, 16));
    mx = fmaxf(mx, __shfl_xor(mx, 32));

    if (__any(mx > m_s + 8.0f)) {  // defer-max: rescale only on real growth
      const float mnew = fmaxf(m_s, mx);
      const float sc = exp2f(m_s - mnew);
      m_s = mnew;
      l_s *= sc;
#pragma unroll
      for (int r = 0; r < 4; ++r) {
        const float scr = __shfl(sc, 4 * lkh + r);  // sc lives at lane q (lr==q)
        o_acc[0][r] *= scr; o_acc[1][r] *= scr;
        o_acc[2][r] *= scr; o_acc[3][r] *= scr;
      }
    }

    float rs = 0.f;
    float pe[4][4];
#pragma unroll
    for (int nt = 0; nt < 4; ++nt)
#pragma unroll
      for (int r = 0; r < 4; ++r) {
        pe[nt][r] = exp2f(s_acc[nt][r] - m_s);
        rs += pe[nt][r];
      }
    rs += __shfl_xor(rs, 16);
    rs += __shfl_xor(rs, 32);
    l_s += rs;

    // ---- P[q=lr][kv=nt*16+4*lkh+0..3] as packed bf16 (one b64 per nt) ----
#pragma unroll
    for (int nt = 0; nt < 4; ++nt) {
      u32x2 pk;
      pk.x = pack2bf(pe[nt][0], pe[nt][1]);
      pk.y = pack2bf(pe[nt][2], pe[nt][3]);
      *reinterpret_cast<u32x2*>(&p_lds[w * 16 + lr][nt * 16 + 4 * lkh]) = pk;
    }

    // ---- O += P @ V ----
#pragma unroll
    for (int kk = 0; kk < 2; ++kk) {
      s16x8 pf = *reinterpret_cast<const s16x8*>(&p_lds[w * 16 + lr][kk * 32 + lkh * 8]);
#pragma unroll
      for (int nt = 0; nt < 4; ++nt) {
        s16x8 vf = *reinterpret_cast<const s16x8*>(&vt_lds[cur][nt * 16 + lr][kk * 32 + lkh * 8]);
        o_acc[nt] = __builtin_amdgcn_mfma_f32_16x16x32_bf16(pf, vf, o_acc[nt], 0, 0, 0);
      }
    }

    // ---- write next V^T into the other buffer ----
    if (pre) {
      const int kv0 = w * 8;
      *reinterpret_cast<s16x8*>(&vt_lds[nxt][l][kv0]) = vreg0;
      *reinterpret_cast<s16x8*>(&vt_lds[nxt][l][32 + kv0]) = vreg1;
    }
    __syncthreads();
  }

  // ---- epilogue: o_acc[nt][r] = O[q=4*lkh+r][d=nt*16+lr] ----
#pragma unroll
  for (int r = 0; r < 4; ++r) {
    const float lv = __shfl(l_s, 4 * lkh + r);
    const float inv = 1.0f / lv;
    const size_t row = rowbase + qt * 64 + w * 16 + lkh * 4 + r;
#pragma unroll
    for (int nt = 0; nt < 4; ++nt) {
      vals[row * 1024 + h * 64 + nt * 16 + lr] = f2bf(o_acc[nt][r] * inv);
    }
  }
}

extern "C" void kernel_launch(void* const* d_in, const int* in_sizes, int n_in,
                              void* d_out, int out_size, void* d_ws, size_t ws_size,
                              hipStream_t stream) {
  const float* x     = (const float*)d_in[0];   // [4,2048,1024]
  const float* w_qkv = (const float*)d_in[1];   // [3072,1024]
  const float* b_qkv = (const float*)d_in[2];   // [3072]
  const float* w_o   = (const float*)d_in[3];   // [1024,1024]
  const float* b_o   = (const float*)d_in[4];   // [1024]
  float* out = (float*)d_out;                   // [4,2048,1024] fp32

  unsigned short* qkv_ws  = (unsigned short*)d_ws;                 // 8192x3072 bf16
  unsigned short* vals_ws = qkv_ws + (size_t)8192 * 3072;          // 8192x1024 bf16

  gemm_bt<true, false><<<dim3(3072 / 128, 8192 / 128), 256, 0, stream>>>(
      x, w_qkv, b_qkv, qkv_ws, 8192, 3072, 1024);
  attn_kernel<<<dim3(2048 / 64, 64), 256, 0, stream>>>(qkv_ws, vals_ws);
  gemm_bt<false, true><<<dim3(1024 / 128, 8192 / 128), 256, 0, stream>>>(
      vals_ws, w_o, b_o, out, 8192, 1024, 1024);
}

// Round 5
// 300.151 us; speedup vs baseline: 1.4750x; 1.0067x over previous
//
#include <hip/hip_runtime.h>
#include <hip/hip_bf16.h>

// MHA fused pipeline: B=4, S=2048, D=1024, H=16, HD=64.
//   k1: qkv = x @ w_qkv^T + b_qkv, epilogue SCATTERS to Q[bh][s][64],
//       K[bh][s][64], VT[bh][d][s]  (fp32 in -> bf16 ws)
//   k2: flash attention, swapped-QK^T lane-local softmax, defer-max
//   k3: out = vals @ w_o^T + b_o          (bf16 in -> fp32 out)

typedef __attribute__((ext_vector_type(4))) float f32x4;
typedef __attribute__((ext_vector_type(8))) short s16x8;
typedef __attribute__((ext_vector_type(2))) unsigned u32x2;
typedef __attribute__((ext_vector_type(4))) unsigned u32x4;

constexpr size_t PART_ELEMS = (size_t)8192 * 1024;  // one of Q/K/VT planes

__device__ __forceinline__ unsigned short f2bf(float f) {
  __hip_bfloat16 h = __float2bfloat16(f);
  unsigned short u;
  __builtin_memcpy(&u, &h, 2);
  return u;
}
__device__ __forceinline__ unsigned pack2bf(float a, float b) {
  return (unsigned)f2bf(a) | ((unsigned)f2bf(b) << 16);
}
__device__ __forceinline__ float bf2f(unsigned short u) {
  union { unsigned u; float f; } v; v.u = ((unsigned)u) << 16;
  return v.f;
}

// C[M,N] = A[M,K] @ Bw[N,K]^T + bias.
// SCATTER: N=3072 qkv output -> Q/K/VT planes in ws (bf16).
template <bool A_F32, bool OUT_F32, bool SCATTER>
__global__ __launch_bounds__(256) void gemm_bt(
    const void* __restrict__ Aptr, const float* __restrict__ Bw,
    const float* __restrict__ bias, void* __restrict__ Cptr,
    int M, int N, int K) {
  __shared__ short lds_a[128][40];
  __shared__ short lds_b[128][40];
  const int t = threadIdx.x;
  const int l = t & 63;
  const int w = t >> 6;
  const int bm = blockIdx.y * 128;
  const int bn = blockIdx.x * 128;
  const int wr = (w >> 1) * 64;
  const int wc = (w & 1) * 64;
  const int lr = l & 15;
  const int lk = (l >> 4) * 8;

  f32x4 acc[4][4] = {};

  for (int k0 = 0; k0 < K; k0 += 32) {
    if (A_F32) {
      const float* A = (const float*)Aptr;
#pragma unroll
      for (int p = 0; p < 4; ++p) {
        const int row = (t >> 3) + p * 32;
        const int col = (t & 7) * 4;
        f32x4 v = *reinterpret_cast<const f32x4*>(&A[(size_t)(bm + row) * K + k0 + col]);
        u32x2 pk;
        pk.x = pack2bf(v.x, v.y);
        pk.y = pack2bf(v.z, v.w);
        *reinterpret_cast<u32x2*>(&lds_a[row][col]) = pk;
      }
    } else {
      const unsigned short* A = (const unsigned short*)Aptr;
#pragma unroll
      for (int p = 0; p < 2; ++p) {
        const int row = (t >> 2) + p * 64;
        const int col = (t & 3) * 8;
        s16x8 v = *reinterpret_cast<const s16x8*>(&A[(size_t)(bm + row) * K + k0 + col]);
        *reinterpret_cast<s16x8*>(&lds_a[row][col]) = v;
      }
    }
#pragma unroll
    for (int p = 0; p < 4; ++p) {
      const int row = (t >> 3) + p * 32;
      const int col = (t & 7) * 4;
      f32x4 v = *reinterpret_cast<const f32x4*>(&Bw[(size_t)(bn + row) * K + k0 + col]);
      u32x2 pk;
      pk.x = pack2bf(v.x, v.y);
      pk.y = pack2bf(v.z, v.w);
      *reinterpret_cast<u32x2*>(&lds_b[row][col]) = pk;
    }
    __syncthreads();

    s16x8 af[4], bfr[4];
#pragma unroll
    for (int mt = 0; mt < 4; ++mt)
      af[mt] = *reinterpret_cast<const s16x8*>(&lds_a[wr + mt * 16 + lr][lk]);
#pragma unroll
    for (int nt = 0; nt < 4; ++nt)
      bfr[nt] = *reinterpret_cast<const s16x8*>(&lds_b[wc + nt * 16 + lr][lk]);
#pragma unroll
    for (int mt = 0; mt < 4; ++mt)
#pragma unroll
      for (int nt = 0; nt < 4; ++nt)
        acc[mt][nt] = __builtin_amdgcn_mfma_f32_16x16x32_bf16(af[mt], bfr[nt], acc[mt][nt], 0, 0, 0);
    __syncthreads();
  }

#pragma unroll
  for (int mt = 0; mt < 4; ++mt) {
#pragma unroll
    for (int nt = 0; nt < 4; ++nt) {
#pragma unroll
      for (int r = 0; r < 4; ++r) {
        const int row = bm + wr + mt * 16 + (l >> 4) * 4 + r;
        const int col = bn + wc + nt * 16 + lr;
        const float vv = acc[mt][nt][r] + bias[col];
        if (SCATTER) {
          const int h = col / 192;            // magic-mul
          const int rem = col - h * 192;
          const int part = rem >> 6;          // 0=Q 1=K 2=V
          const int d = rem & 63;
          const int s = row & 2047;
          const size_t bh = (size_t)(row >> 11) * 16 + h;
          unsigned short* W = (unsigned short*)Cptr;
          size_t off;
          if (part == 2)
            off = 2 * PART_ELEMS + (bh * 64 + d) * 2048 + s;       // VT[bh][d][s]
          else
            off = (size_t)part * PART_ELEMS + (bh * 2048 + s) * 64 + d;  // Q/K[bh][s][d]
          W[off] = f2bf(vv);
        } else if (OUT_F32) {
          ((float*)Cptr)[(size_t)row * N + col] = vv;
        } else {
          ((unsigned short*)Cptr)[(size_t)row * N + col] = f2bf(vv);
        }
      }
    }
  }
}

// Flash attention over ws planes Q[bh][s][64], K[bh][s][64], VT[bh][d][s].
// Swapped QK^T -> lane-local softmax; defer-max (THR=8, exp2 domain).
// K and VT single-buffered (write between the two barriers). LDS 27 KB.
__global__ __launch_bounds__(256, 5) void attn_kernel(
    const unsigned short* __restrict__ ws, unsigned short* __restrict__ vals) {
  __shared__ short k_lds[64][72];
  __shared__ short vt_lds[64][72];   // vt[d][kv]
  __shared__ short p_lds[64][72];    // Q staging at init, then P[q][kv]
  const int t = threadIdx.x;
  const int l = t & 63;
  const int w = t >> 6;
  const int lr = l & 15;
  const int lkh = l >> 4;
  const int qt = blockIdx.x;
  const int bh = blockIdx.y;
  const int b = bh >> 4;
  const int h = bh & 15;
  const unsigned short* Qh  = ws + (size_t)bh * (2048 * 64);
  const unsigned short* Kh  = ws + PART_ELEMS + (size_t)bh * (2048 * 64);
  const unsigned short* VTh = ws + 2 * PART_ELEMS + (size_t)bh * (64 * 2048);

  const int srow = t >> 2;         // 0..63
  const int scol = (t & 3) * 16;   // 0,16,32,48

  // ---- stage Q (scaled by 1/8 * log2e; softmax in exp2 domain) ----
  const float qscale = 0.125f * 1.44269504f;
  {
    const unsigned short* src = Qh + (size_t)qt * 4096 + srow * 64 + scol;
    s16x8 a0 = *reinterpret_cast<const s16x8*>(src);
    s16x8 a1 = *reinterpret_cast<const s16x8*>(src + 8);
    u32x4 q0, q1;
#pragma unroll
    for (int j = 0; j < 4; ++j) {
      q0[j] = pack2bf(bf2f((unsigned short)a0[2 * j]) * qscale,
                      bf2f((unsigned short)a0[2 * j + 1]) * qscale);
      q1[j] = pack2bf(bf2f((unsigned short)a1[2 * j]) * qscale,
                      bf2f((unsigned short)a1[2 * j + 1]) * qscale);
    }
    *reinterpret_cast<u32x4*>(&p_lds[srow][scol]) = q0;
    *reinterpret_cast<u32x4*>(&p_lds[srow][scol + 8]) = q1;
  }
  // ---- stage K tile 0 / VT tile 0 ----
  {
    const unsigned short* ks = Kh + srow * 64 + scol;
    *reinterpret_cast<s16x8*>(&k_lds[srow][scol]) = *reinterpret_cast<const s16x8*>(ks);
    *reinterpret_cast<s16x8*>(&k_lds[srow][scol + 8]) = *reinterpret_cast<const s16x8*>(ks + 8);
    const unsigned short* vs = VTh + (size_t)srow * 2048 + scol;
    *reinterpret_cast<s16x8*>(&vt_lds[srow][scol]) = *reinterpret_cast<const s16x8*>(vs);
    *reinterpret_cast<s16x8*>(&vt_lds[srow][scol + 8]) = *reinterpret_cast<const s16x8*>(vs + 8);
  }
  __syncthreads();

  // Q fragments -> registers; p_lds reused for P (wave-local rows)
  s16x8 qf0 = *reinterpret_cast<const s16x8*>(&p_lds[w * 16 + lr][lkh * 8]);
  s16x8 qf1 = *reinterpret_cast<const s16x8*>(&p_lds[w * 16 + lr][32 + lkh * 8]);

  f32x4 o_acc[4] = {};
  float m_s = -1e30f;
  float l_s = 0.f;

  for (int kt = 0; kt < 32; ++kt) {
    const bool pre = (kt + 1) < 32;

    // ---- issue next K/VT loads early (latency hides under MFMA+softmax) ----
    s16x8 kr0, kr1, vr0, vr1;
    if (pre) {
      const unsigned short* ks = Kh + (size_t)(kt + 1) * 4096 + srow * 64 + scol;
      kr0 = *reinterpret_cast<const s16x8*>(ks);
      kr1 = *reinterpret_cast<const s16x8*>(ks + 8);
      const unsigned short* vs = VTh + (size_t)srow * 2048 + (kt + 1) * 64 + scol;
      vr0 = *reinterpret_cast<const s16x8*>(vs);
      vr1 = *reinterpret_cast<const s16x8*>(vs + 8);
    }

    // ---- S^T = K Q^T (swapped operands) ----
    f32x4 s_acc[4] = {};
#pragma unroll
    for (int nt = 0; nt < 4; ++nt) {
      s16x8 kf0 = *reinterpret_cast<const s16x8*>(&k_lds[nt * 16 + lr][lkh * 8]);
      s16x8 kf1 = *reinterpret_cast<const s16x8*>(&k_lds[nt * 16 + lr][32 + lkh * 8]);
      s_acc[nt] = __builtin_amdgcn_mfma_f32_16x16x32_bf16(kf0, qf0, s_acc[nt], 0, 0, 0);
      s_acc[nt] = __builtin_amdgcn_mfma_f32_16x16x32_bf16(kf1, qf1, s_acc[nt], 0, 0, 0);
    }

    // ---- softmax: lane holds S^T[kv = nt*16+lkh*4+r][q = lr] ----
    float mx = -1e30f;
#pragma unroll
    for (int nt = 0; nt < 4; ++nt)
      mx = fmaxf(mx, fmaxf(fmaxf(s_acc[nt][0], s_acc[nt][1]),
                           fmaxf(s_acc[nt][2], s_acc[nt][3])));
    mx = fmaxf(mx, __shfl_xor(mx, 16));
    mx = fmaxf(mx, __shfl_xor(mx, 32));

    if (__any(mx > m_s + 8.0f)) {  // defer-max
      const float mnew = fmaxf(m_s, mx);
      const float sc = exp2f(m_s - mnew);
      m_s = mnew;
      l_s *= sc;
#pragma unroll
      for (int r = 0; r < 4; ++r) {
        const float scr = __shfl(sc, 4 * lkh + r);
        o_acc[0][r] *= scr; o_acc[1][r] *= scr;
        o_acc[2][r] *= scr; o_acc[3][r] *= scr;
      }
    }

    float rs = 0.f;
    float pe[4][4];
#pragma unroll
    for (int nt = 0; nt < 4; ++nt)
#pragma unroll
      for (int r = 0; r < 4; ++r) {
        pe[nt][r] = exp2f(s_acc[nt][r] - m_s);
        rs += pe[nt][r];
      }
    rs += __shfl_xor(rs, 16);
    rs += __shfl_xor(rs, 32);
    l_s += rs;

    // ---- P[q=lr][kv=nt*16+4*lkh+0..3] packed bf16 ----
#pragma unroll
    for (int nt = 0; nt < 4; ++nt) {
      u32x2 pk;
      pk.x = pack2bf(pe[nt][0], pe[nt][1]);
      pk.y = pack2bf(pe[nt][2], pe[nt][3]);
      *reinterpret_cast<u32x2*>(&p_lds[w * 16 + lr][nt * 16 + 4 * lkh]) = pk;
    }

    // ---- O += P @ V ----
#pragma unroll
    for (int kk = 0; kk < 2; ++kk) {
      s16x8 pf = *reinterpret_cast<const s16x8*>(&p_lds[w * 16 + lr][kk * 32 + lkh * 8]);
#pragma unroll
      for (int nt = 0; nt < 4; ++nt) {
        s16x8 vf = *reinterpret_cast<const s16x8*>(&vt_lds[nt * 16 + lr][kk * 32 + lkh * 8]);
        o_acc[nt] = __builtin_amdgcn_mfma_f32_16x16x32_bf16(pf, vf, o_acc[nt], 0, 0, 0);
      }
    }
    __syncthreads();  // all reads of k_lds/vt_lds done

    // ---- write next tiles ----
    if (pre) {
      *reinterpret_cast<s16x8*>(&k_lds[srow][scol]) = kr0;
      *reinterpret_cast<s16x8*>(&k_lds[srow][scol + 8]) = kr1;
      *reinterpret_cast<s16x8*>(&vt_lds[srow][scol]) = vr0;
      *reinterpret_cast<s16x8*>(&vt_lds[srow][scol + 8]) = vr1;
    }
    __syncthreads();
  }

  // ---- epilogue: o_acc[nt][r] = O[q=w*16+4*lkh+r][d=nt*16+lr] ----
#pragma unroll
  for (int r = 0; r < 4; ++r) {
    const float lv = __shfl(l_s, 4 * lkh + r);
    const float inv = 1.0f / lv;
    const size_t row = (size_t)b * 2048 + qt * 64 + w * 16 + lkh * 4 + r;
#pragma unroll
    for (int nt = 0; nt < 4; ++nt) {
      vals[row * 1024 + h * 64 + nt * 16 + lr] = f2bf(o_acc[nt][r] * inv);
    }
  }
}

extern "C" void kernel_launch(void* const* d_in, const int* in_sizes, int n_in,
                              void* d_out, int out_size, void* d_ws, size_t ws_size,
                              hipStream_t stream) {
  const float* x     = (const float*)d_in[0];   // [4,2048,1024]
  const float* w_qkv = (const float*)d_in[1];   // [3072,1024]
  const float* b_qkv = (const float*)d_in[2];   // [3072]
  const float* w_o   = (const float*)d_in[3];   // [1024,1024]
  const float* b_o   = (const float*)d_in[4];   // [1024]
  float* out = (float*)d_out;                   // [4,2048,1024] fp32

  unsigned short* ws      = (unsigned short*)d_ws;           // Q | K | VT planes
  unsigned short* vals_ws = ws + 3 * PART_ELEMS;             // 8192x1024 bf16

  gemm_bt<true, false, true><<<dim3(3072 / 128, 8192 / 128), 256, 0, stream>>>(
      x, w_qkv, b_qkv, ws, 8192, 3072, 1024);
  attn_kernel<<<dim3(2048 / 64, 64), 256, 0, stream>>>(ws, vals_ws);
  gemm_bt<false, true, false><<<dim3(1024 / 128, 8192 / 128), 256, 0, stream>>>(
      vals_ws, w_o, b_o, out, 8192, 1024, 1024);
}

// Round 6
// 265.107 us; speedup vs baseline: 1.6699x; 1.1322x over previous
//
#include <hip/hip_runtime.h>
#include <hip/hip_bf16.h>

// MHA fused pipeline: B=4, S=2048, D=1024, H=16, HD=64.
//   k1: qkv = x @ w_qkv^T + b_qkv, epilogue SCATTERS to Q[bh][s][64] (pre-scaled
//       by 0.125*log2e), K[bh][s][64], VT[bh][d][s]  (fp32 in -> bf16 ws)
//   k2: flash attention, 32 q-rows/wave, XOR-swizzled LDS, lane-local softmax
//   k3: out = vals @ w_o^T + b_o          (bf16 in -> fp32 out)

typedef __attribute__((ext_vector_type(4))) float f32x4;
typedef __attribute__((ext_vector_type(8))) short s16x8;
typedef __attribute__((ext_vector_type(2))) unsigned u32x2;

constexpr size_t PART_ELEMS = (size_t)8192 * 1024;  // one of Q/K/VT planes

__device__ __forceinline__ unsigned short f2bf(float f) {
  __hip_bfloat16 h = __float2bfloat16(f);
  unsigned short u;
  __builtin_memcpy(&u, &h, 2);
  return u;
}
__device__ __forceinline__ unsigned pack2bf(float a, float b) {
  return (unsigned)f2bf(a) | ((unsigned)f2bf(b) << 16);
}
__device__ __forceinline__ float bf2f(unsigned short u) {
  union { unsigned u; float f; } v; v.u = ((unsigned)u) << 16;
  return v.f;
}
__device__ __forceinline__ float fexp2(float x) {
#if __has_builtin(__builtin_amdgcn_exp2f)
  return __builtin_amdgcn_exp2f(x);
#else
  float r; asm("v_exp_f32 %0, %1" : "=v"(r) : "v"(x)); return r;
#endif
}
// XOR-swizzled short-index into a [rows][64]-short tile (128 B rows, 8x 16B units).
__device__ __forceinline__ int swzs(int row, int col) {
  return row * 64 + (((col >> 3) ^ (row & 7)) << 3) + (col & 7);
}

// C[M,N] = A[M,K] @ Bw[N,K]^T + bias.
// SCATTER: N=3072 qkv output -> Q/K/VT planes in ws (bf16), Q pre-scaled.
template <bool A_F32, bool OUT_F32, bool SCATTER>
__global__ __launch_bounds__(256) void gemm_bt(
    const void* __restrict__ Aptr, const float* __restrict__ Bw,
    const float* __restrict__ bias, void* __restrict__ Cptr,
    int M, int N, int K) {
  __shared__ short lds_a[128][40];
  __shared__ short lds_b[128][40];
  const int t = threadIdx.x;
  const int l = t & 63;
  const int w = t >> 6;
  const int bm = blockIdx.y * 128;
  const int bn = blockIdx.x * 128;
  const int wr = (w >> 1) * 64;
  const int wc = (w & 1) * 64;
  const int lr = l & 15;
  const int lk = (l >> 4) * 8;

  f32x4 acc[4][4] = {};

  for (int k0 = 0; k0 < K; k0 += 32) {
    if (A_F32) {
      const float* A = (const float*)Aptr;
#pragma unroll
      for (int p = 0; p < 4; ++p) {
        const int row = (t >> 3) + p * 32;
        const int col = (t & 7) * 4;
        f32x4 v = *reinterpret_cast<const f32x4*>(&A[(size_t)(bm + row) * K + k0 + col]);
        u32x2 pk;
        pk.x = pack2bf(v.x, v.y);
        pk.y = pack2bf(v.z, v.w);
        *reinterpret_cast<u32x2*>(&lds_a[row][col]) = pk;
      }
    } else {
      const unsigned short* A = (const unsigned short*)Aptr;
#pragma unroll
      for (int p = 0; p < 2; ++p) {
        const int row = (t >> 2) + p * 64;
        const int col = (t & 3) * 8;
        s16x8 v = *reinterpret_cast<const s16x8*>(&A[(size_t)(bm + row) * K + k0 + col]);
        *reinterpret_cast<s16x8*>(&lds_a[row][col]) = v;
      }
    }
#pragma unroll
    for (int p = 0; p < 4; ++p) {
      const int row = (t >> 3) + p * 32;
      const int col = (t & 7) * 4;
      f32x4 v = *reinterpret_cast<const f32x4*>(&Bw[(size_t)(bn + row) * K + k0 + col]);
      u32x2 pk;
      pk.x = pack2bf(v.x, v.y);
      pk.y = pack2bf(v.z, v.w);
      *reinterpret_cast<u32x2*>(&lds_b[row][col]) = pk;
    }
    __syncthreads();

    s16x8 af[4], bfr[4];
#pragma unroll
    for (int mt = 0; mt < 4; ++mt)
      af[mt] = *reinterpret_cast<const s16x8*>(&lds_a[wr + mt * 16 + lr][lk]);
#pragma unroll
    for (int nt = 0; nt < 4; ++nt)
      bfr[nt] = *reinterpret_cast<const s16x8*>(&lds_b[wc + nt * 16 + lr][lk]);
#pragma unroll
    for (int mt = 0; mt < 4; ++mt)
#pragma unroll
      for (int nt = 0; nt < 4; ++nt)
        acc[mt][nt] = __builtin_amdgcn_mfma_f32_16x16x32_bf16(af[mt], bfr[nt], acc[mt][nt], 0, 0, 0);
    __syncthreads();
  }

#pragma unroll
  for (int mt = 0; mt < 4; ++mt) {
#pragma unroll
    for (int nt = 0; nt < 4; ++nt) {
#pragma unroll
      for (int r = 0; r < 4; ++r) {
        const int row = bm + wr + mt * 16 + (l >> 4) * 4 + r;
        const int col = bn + wc + nt * 16 + lr;
        const float vv = acc[mt][nt][r] + bias[col];
        if (SCATTER) {
          const int h = col / 192;
          const int rem = col - h * 192;
          const int part = rem >> 6;          // 0=Q 1=K 2=V
          const int d = rem & 63;
          const int s = row & 2047;
          const size_t bh = (size_t)(row >> 11) * 16 + h;
          unsigned short* W = (unsigned short*)Cptr;
          float vvv = vv;
          if (part == 0) vvv *= 0.1803368801f;  // 0.125 * log2e
          size_t off;
          if (part == 2)
            off = 2 * PART_ELEMS + (bh * 64 + d) * 2048 + s;             // VT[bh][d][s]
          else
            off = (size_t)part * PART_ELEMS + (bh * 2048 + s) * 64 + d;  // Q/K[bh][s][d]
          W[off] = f2bf(vvv);
        } else if (OUT_F32) {
          ((float*)Cptr)[(size_t)row * N + col] = vv;
        } else {
          ((unsigned short*)Cptr)[(size_t)row * N + col] = f2bf(vv);
        }
      }
    }
  }
}

// Flash attention over ws planes Q[bh][s][64] (pre-scaled), K[bh][s][64], VT[bh][d][s].
// Block: 128 q-rows, 4 waves (32 q-rows each); KV tile 64. All LDS XOR-swizzled
// at 16B-unit granularity -> conflict-free b128 reads/writes. Swapped QK^T,
// lane-local softmax, defer-max (THR=8, exp2 domain). LDS 32 KB, 4 blk/CU.
__global__ __launch_bounds__(256, 4) void attn_kernel(
    const unsigned short* __restrict__ ws, unsigned short* __restrict__ vals) {
  __shared__ short k_lds[64 * 64];    // [kv][d]
  __shared__ short vt_lds[64 * 64];   // [d][kv]
  __shared__ short p_lds[128 * 64];   // [q][kv]
  const int t = threadIdx.x;
  const int l = t & 63;
  const int w = t >> 6;
  const int lr = l & 15;
  const int lkh = l >> 4;
  const int qt = blockIdx.x;
  const int bh = blockIdx.y;
  const int b = bh >> 4;
  const int h = bh & 15;
  const unsigned short* Qh  = ws + (size_t)bh * (2048 * 64);
  const unsigned short* Kh  = ws + PART_ELEMS + (size_t)bh * (2048 * 64);
  const unsigned short* VTh = ws + 2 * PART_ELEMS + (size_t)bh * (64 * 2048);

  const int srow = t >> 2;         // 0..63
  const int scol = (t & 3) * 16;   // 0,16,32,48

  // ---- Q fragments straight from global (already scaled by 0.125*log2e) ----
  s16x8 qf[2][2];
  {
    const unsigned short* qb = Qh + ((size_t)qt * 128 + w * 32 + lr) * 64 + lkh * 8;
    qf[0][0] = *reinterpret_cast<const s16x8*>(qb);
    qf[0][1] = *reinterpret_cast<const s16x8*>(qb + 32);
    qf[1][0] = *reinterpret_cast<const s16x8*>(qb + 16 * 64);
    qf[1][1] = *reinterpret_cast<const s16x8*>(qb + 16 * 64 + 32);
  }
  // ---- stage K/VT tile 0 ----
  {
    const unsigned short* kp = Kh + (size_t)srow * 64 + scol;
    s16x8 k0 = *reinterpret_cast<const s16x8*>(kp);
    s16x8 k1 = *reinterpret_cast<const s16x8*>(kp + 8);
    const unsigned short* vp = VTh + (size_t)srow * 2048 + scol;
    s16x8 v0 = *reinterpret_cast<const s16x8*>(vp);
    s16x8 v1 = *reinterpret_cast<const s16x8*>(vp + 8);
    *reinterpret_cast<s16x8*>(&k_lds[swzs(srow, scol)])      = k0;
    *reinterpret_cast<s16x8*>(&k_lds[swzs(srow, scol + 8)])  = k1;
    *reinterpret_cast<s16x8*>(&vt_lds[swzs(srow, scol)])     = v0;
    *reinterpret_cast<s16x8*>(&vt_lds[swzs(srow, scol + 8)]) = v1;
  }
  __syncthreads();

  f32x4 o_acc[2][4] = {};
  float m_s[2] = {-1e30f, -1e30f};
  float l_s[2] = {0.f, 0.f};

  for (int kt = 0; kt < 32; ++kt) {
    const bool pre = (kt + 1) < 32;

    // ---- issue next K/VT loads early ----
    s16x8 kr0, kr1, vr0, vr1;
    if (pre) {
      const unsigned short* kp = Kh + ((size_t)(kt + 1) * 64 + srow) * 64 + scol;
      kr0 = *reinterpret_cast<const s16x8*>(kp);
      kr1 = *reinterpret_cast<const s16x8*>(kp + 8);
      const unsigned short* vp = VTh + (size_t)srow * 2048 + (kt + 1) * 64 + scol;
      vr0 = *reinterpret_cast<const s16x8*>(vp);
      vr1 = *reinterpret_cast<const s16x8*>(vp + 8);
    }

    // ---- S^T = K Q^T (swapped); kf shared across both q-halves ----
    f32x4 s_acc[2][4] = {};
    {
      s16x8 kf[4][2];
#pragma unroll
      for (int nt = 0; nt < 4; ++nt) {
        kf[nt][0] = *reinterpret_cast<const s16x8*>(&k_lds[swzs(nt * 16 + lr, lkh * 8)]);
        kf[nt][1] = *reinterpret_cast<const s16x8*>(&k_lds[swzs(nt * 16 + lr, 32 + lkh * 8)]);
      }
#pragma unroll
      for (int qh = 0; qh < 2; ++qh)
#pragma unroll
        for (int nt = 0; nt < 4; ++nt) {
          s_acc[qh][nt] = __builtin_amdgcn_mfma_f32_16x16x32_bf16(kf[nt][0], qf[qh][0], s_acc[qh][nt], 0, 0, 0);
          s_acc[qh][nt] = __builtin_amdgcn_mfma_f32_16x16x32_bf16(kf[nt][1], qf[qh][1], s_acc[qh][nt], 0, 0, 0);
        }
    }

    // ---- softmax per q-half: lane holds S^T[kv=nt*16+4*lkh+r][q=qh*16+lr] ----
#pragma unroll
    for (int qh = 0; qh < 2; ++qh) {
      float mx = fmaxf(
          fmaxf(fmaxf(fmaxf(s_acc[qh][0][0], s_acc[qh][0][1]), fmaxf(s_acc[qh][0][2], s_acc[qh][0][3])),
                fmaxf(fmaxf(s_acc[qh][1][0], s_acc[qh][1][1]), fmaxf(s_acc[qh][1][2], s_acc[qh][1][3]))),
          fmaxf(fmaxf(fmaxf(s_acc[qh][2][0], s_acc[qh][2][1]), fmaxf(s_acc[qh][2][2], s_acc[qh][2][3])),
                fmaxf(fmaxf(s_acc[qh][3][0], s_acc[qh][3][1]), fmaxf(s_acc[qh][3][2], s_acc[qh][3][3]))));
      mx = fmaxf(mx, __shfl_xor(mx, 16));
      mx = fmaxf(mx, __shfl_xor(mx, 32));

      if (__any(mx > m_s[qh] + 8.0f)) {  // defer-max
        const float mnew = fmaxf(m_s[qh], mx);
        const float sc = fexp2(m_s[qh] - mnew);
        m_s[qh] = mnew;
        l_s[qh] *= sc;
#pragma unroll
        for (int r = 0; r < 4; ++r) {
          const float scr = __shfl(sc, 4 * lkh + r);
          o_acc[qh][0][r] *= scr; o_acc[qh][1][r] *= scr;
          o_acc[qh][2][r] *= scr; o_acc[qh][3][r] *= scr;
        }
      }

      float rs = 0.f;
#pragma unroll
      for (int nt = 0; nt < 4; ++nt) {
        float p0 = fexp2(s_acc[qh][nt][0] - m_s[qh]);
        float p1 = fexp2(s_acc[qh][nt][1] - m_s[qh]);
        float p2 = fexp2(s_acc[qh][nt][2] - m_s[qh]);
        float p3 = fexp2(s_acc[qh][nt][3] - m_s[qh]);
        rs += (p0 + p1) + (p2 + p3);
        u32x2 pk;
        pk.x = pack2bf(p0, p1);
        pk.y = pack2bf(p2, p3);
        // P[q = w*32+qh*16+lr][kv = nt*16+4*lkh .. +3]
        *reinterpret_cast<u32x2*>(&p_lds[swzs(w * 32 + qh * 16 + lr, nt * 16 + 4 * lkh)]) = pk;
      }
      rs += __shfl_xor(rs, 16);
      rs += __shfl_xor(rs, 32);
      l_s[qh] += rs;
    }

    // ---- O += P @ V; vf shared across both q-halves ----
    {
      s16x8 vf[4][2];
#pragma unroll
      for (int nt = 0; nt < 4; ++nt) {
        vf[nt][0] = *reinterpret_cast<const s16x8*>(&vt_lds[swzs(nt * 16 + lr, lkh * 8)]);
        vf[nt][1] = *reinterpret_cast<const s16x8*>(&vt_lds[swzs(nt * 16 + lr, 32 + lkh * 8)]);
      }
#pragma unroll
      for (int qh = 0; qh < 2; ++qh) {
        s16x8 pf0 = *reinterpret_cast<const s16x8*>(&p_lds[swzs(w * 32 + qh * 16 + lr, lkh * 8)]);
        s16x8 pf1 = *reinterpret_cast<const s16x8*>(&p_lds[swzs(w * 32 + qh * 16 + lr, 32 + lkh * 8)]);
#pragma unroll
        for (int nt = 0; nt < 4; ++nt) {
          o_acc[qh][nt] = __builtin_amdgcn_mfma_f32_16x16x32_bf16(pf0, vf[nt][0], o_acc[qh][nt], 0, 0, 0);
          o_acc[qh][nt] = __builtin_amdgcn_mfma_f32_16x16x32_bf16(pf1, vf[nt][1], o_acc[qh][nt], 0, 0, 0);
        }
      }
    }
    __syncthreads();  // all reads of k_lds/vt_lds done

    // ---- write next tiles ----
    if (pre) {
      *reinterpret_cast<s16x8*>(&k_lds[swzs(srow, scol)])      = kr0;
      *reinterpret_cast<s16x8*>(&k_lds[swzs(srow, scol + 8)])  = kr1;
      *reinterpret_cast<s16x8*>(&vt_lds[swzs(srow, scol)])     = vr0;
      *reinterpret_cast<s16x8*>(&vt_lds[swzs(srow, scol + 8)]) = vr1;
    }
    __syncthreads();
  }

  // ---- epilogue: o_acc[qh][nt][r] = O[q=w*32+qh*16+4*lkh+r][d=nt*16+lr] ----
#pragma unroll
  for (int qh = 0; qh < 2; ++qh) {
#pragma unroll
    for (int r = 0; r < 4; ++r) {
      const float lv = __shfl(l_s[qh], 4 * lkh + r);
      const float inv = 1.0f / lv;
      const size_t row = (size_t)b * 2048 + qt * 128 + w * 32 + qh * 16 + lkh * 4 + r;
#pragma unroll
      for (int nt = 0; nt < 4; ++nt) {
        vals[row * 1024 + h * 64 + nt * 16 + lr] = f2bf(o_acc[qh][nt][r] * inv);
      }
    }
  }
}

extern "C" void kernel_launch(void* const* d_in, const int* in_sizes, int n_in,
                              void* d_out, int out_size, void* d_ws, size_t ws_size,
                              hipStream_t stream) {
  const float* x     = (const float*)d_in[0];   // [4,2048,1024]
  const float* w_qkv = (const float*)d_in[1];   // [3072,1024]
  const float* b_qkv = (const float*)d_in[2];   // [3072]
  const float* w_o   = (const float*)d_in[3];   // [1024,1024]
  const float* b_o   = (const float*)d_in[4];   // [1024]
  float* out = (float*)d_out;                   // [4,2048,1024] fp32

  unsigned short* ws      = (unsigned short*)d_ws;           // Q | K | VT planes
  unsigned short* vals_ws = ws + 3 * PART_ELEMS;             // 8192x1024 bf16

  gemm_bt<true, false, true><<<dim3(3072 / 128, 8192 / 128), 256, 0, stream>>>(
      x, w_qkv, b_qkv, ws, 8192, 3072, 1024);
  attn_kernel<<<dim3(2048 / 128, 64), 256, 0, stream>>>(ws, vals_ws);
  gemm_bt<false, true, false><<<dim3(1024 / 128, 8192 / 128), 256, 0, stream>>>(
      vals_ws, w_o, b_o, out, 8192, 1024, 1024);
}

// Round 7
// 255.841 us; speedup vs baseline: 1.7304x; 1.0362x over previous
//
#include <hip/hip_runtime.h>
#include <hip/hip_bf16.h>

// MHA fused pipeline: B=4, S=2048, D=1024, H=16, HD=64.
//   k0: x fp32 -> xb bf16 (once)
//   k1: qkv = xb @ w_qkv^T + b_qkv, epilogue SCATTERS to Q[bh][s][64] (pre-scaled
//       by 0.125*log2e), K[bh][s][64], VT[bh][d][s]   (A via global_load_lds)
//   k2: flash attention (unchanged R6), writes vals into xb region (aliased)
//   k3: out = vals @ w_o^T + b_o  (same GEMM, fp32 out)
// ws usage: [xb|vals 16.8MB][Q 16.8][K 16.8][VT 16.8] = 67.1 MB total.

typedef __attribute__((ext_vector_type(4))) float f32x4;
typedef __attribute__((ext_vector_type(8))) short s16x8;
typedef __attribute__((ext_vector_type(2))) unsigned u32x2;
typedef __attribute__((ext_vector_type(4))) unsigned u32x4;

constexpr size_t PART_ELEMS = (size_t)8192 * 1024;  // one bf16 plane

__device__ __forceinline__ unsigned short f2bf(float f) {
  __hip_bfloat16 h = __float2bfloat16(f);
  unsigned short u;
  __builtin_memcpy(&u, &h, 2);
  return u;
}
__device__ __forceinline__ unsigned pack2bf(float a, float b) {
  return (unsigned)f2bf(a) | ((unsigned)f2bf(b) << 16);
}
__device__ __forceinline__ float bf2f(unsigned short u) {
  union { unsigned u; float f; } v; v.u = ((unsigned)u) << 16;
  return v.f;
}
__device__ __forceinline__ float fexp2(float x) {
#if __has_builtin(__builtin_amdgcn_exp2f)
  return __builtin_amdgcn_exp2f(x);
#else
  float r; asm("v_exp_f32 %0, %1" : "=v"(r) : "v"(x)); return r;
#endif
}
// async global->LDS, 16B per lane. LDS dest is wave-uniform base + lane*16.
__device__ __forceinline__ void gload_lds16(const void* g, void* l) {
  __builtin_amdgcn_global_load_lds(
      (const __attribute__((address_space(1))) unsigned*)g,
      (__attribute__((address_space(3))) unsigned*)l, 16, 0, 0);
}
// XOR-swizzled short-index into a [rows][64]-short tile (attn LDS).
__device__ __forceinline__ int swzs(int row, int col) {
  return row * 64 + (((col >> 3) ^ (row & 7)) << 3) + (col & 7);
}

// ---- k0: fp32 -> bf16 convert (x only), 8 elems/thread ----
__global__ __launch_bounds__(256) void cvt_kernel(const float* __restrict__ in,
                                                  unsigned short* __restrict__ out) {
  const size_t i = ((size_t)blockIdx.x * 256 + threadIdx.x) * 8;
  f32x4 v0 = *reinterpret_cast<const f32x4*>(in + i);
  f32x4 v1 = *reinterpret_cast<const f32x4*>(in + i + 4);
  u32x4 pk;
  pk.x = pack2bf(v0.x, v0.y); pk.y = pack2bf(v0.z, v0.w);
  pk.z = pack2bf(v1.x, v1.y); pk.w = pack2bf(v1.z, v1.w);
  *reinterpret_cast<u32x4*>(out + i) = pk;
}

// C[M,N] = A[M,K](bf16) @ Bw[N,K](fp32)^T + bias.
// A staged via global_load_lds into linear [128][32]; B reg-staged+converted.
// SCATTER: qkv output -> Q/K/VT planes (Q pre-scaled). Else fp32 C out.
template <bool SCATTER>
__global__ __launch_bounds__(256) void gemm_a16(
    const unsigned short* __restrict__ A, const float* __restrict__ Bw,
    const float* __restrict__ bias, void* __restrict__ Cptr,
    int M, int N, int K) {
  __shared__ short lds_a[128 * 32];
  __shared__ short lds_b[128 * 32];
  const int t = threadIdx.x;
  const int l = t & 63;
  const int w = t >> 6;
  const int bm = blockIdx.y * 128;
  const int bn = blockIdx.x * 128;
  const int wr = (w >> 1) * 64;
  const int wc = (w & 1) * 64;
  const int lr = l & 15;
  const int lk = (l >> 4) * 8;

  f32x4 acc[4][4] = {};

  // A staging: wave w covers rows [w*16, w*16+16) and [64+w*16, 64+w*16+16)
  const int arow = w * 16 + (l >> 2);
  const int acol = (l & 3) * 8;
  short* adst0 = &lds_a[(w * 16) * 32];
  short* adst1 = &lds_a[(64 + w * 16) * 32];

  for (int k0 = 0; k0 < K; k0 += 32) {
    // ---- issue async A-tile loads (vmcnt drained at the barrier) ----
    const unsigned short* as = &A[(size_t)(bm + arow) * K + k0 + acol];
    gload_lds16(as, adst0);
    gload_lds16(as + (size_t)64 * K, adst1);
    // ---- stage B tile (fp32 -> bf16), conflict-free b128 writes ----
#pragma unroll
    for (int p = 0; p < 2; ++p) {
      const int row = (t >> 2) + p * 64;
      const int col = (t & 3) * 8;
      const float* src = &Bw[(size_t)(bn + row) * K + k0 + col];
      f32x4 v0 = *reinterpret_cast<const f32x4*>(src);
      f32x4 v1 = *reinterpret_cast<const f32x4*>(src + 4);
      u32x4 pk;
      pk.x = pack2bf(v0.x, v0.y); pk.y = pack2bf(v0.z, v0.w);
      pk.z = pack2bf(v1.x, v1.y); pk.w = pack2bf(v1.z, v1.w);
      *reinterpret_cast<u32x4*>(&lds_b[row * 32 + col]) = pk;
    }
    __syncthreads();

    s16x8 af[4], bfr[4];
#pragma unroll
    for (int mt = 0; mt < 4; ++mt)
      af[mt] = *reinterpret_cast<const s16x8*>(&lds_a[(wr + mt * 16 + lr) * 32 + lk]);
#pragma unroll
    for (int nt = 0; nt < 4; ++nt)
      bfr[nt] = *reinterpret_cast<const s16x8*>(&lds_b[(wc + nt * 16 + lr) * 32 + lk]);
#pragma unroll
    for (int mt = 0; mt < 4; ++mt)
#pragma unroll
      for (int nt = 0; nt < 4; ++nt)
        acc[mt][nt] = __builtin_amdgcn_mfma_f32_16x16x32_bf16(af[mt], bfr[nt], acc[mt][nt], 0, 0, 0);
    __syncthreads();
  }

#pragma unroll
  for (int mt = 0; mt < 4; ++mt) {
#pragma unroll
    for (int nt = 0; nt < 4; ++nt) {
#pragma unroll
      for (int r = 0; r < 4; ++r) {
        const int row = bm + wr + mt * 16 + (l >> 4) * 4 + r;
        const int col = bn + wc + nt * 16 + lr;
        const float vv = acc[mt][nt][r] + bias[col];
        if (SCATTER) {
          const int h = col / 192;
          const int rem = col - h * 192;
          const int part = rem >> 6;          // 0=Q 1=K 2=V
          const int d = rem & 63;
          const int s = row & 2047;
          const size_t bh = (size_t)(row >> 11) * 16 + h;
          unsigned short* W = (unsigned short*)Cptr;
          float vvv = vv;
          if (part == 0) vvv *= 0.1803368801f;  // 0.125 * log2e
          size_t off;
          if (part == 2)
            off = 2 * PART_ELEMS + (bh * 64 + d) * 2048 + s;             // VT[bh][d][s]
          else
            off = (size_t)part * PART_ELEMS + (bh * 2048 + s) * 64 + d;  // Q/K[bh][s][d]
          W[off] = f2bf(vvv);
        } else {
          ((float*)Cptr)[(size_t)row * N + col] = vv;
        }
      }
    }
  }
}

// Flash attention over planes Q[bh][s][64] (pre-scaled), K[bh][s][64], VT[bh][d][s].
// Block: 128 q-rows, 4 waves (32 q-rows each); KV tile 64. XOR-swizzled LDS,
// swapped QK^T, lane-local softmax, defer-max. LDS 32 KB, 4 blk/CU.
__global__ __launch_bounds__(256, 4) void attn_kernel(
    const unsigned short* __restrict__ ws, unsigned short* __restrict__ vals) {
  __shared__ short k_lds[64 * 64];
  __shared__ short vt_lds[64 * 64];
  __shared__ short p_lds[128 * 64];
  const int t = threadIdx.x;
  const int l = t & 63;
  const int w = t >> 6;
  const int lr = l & 15;
  const int lkh = l >> 4;
  const int qt = blockIdx.x;
  const int bh = blockIdx.y;
  const int b = bh >> 4;
  const int h = bh & 15;
  const unsigned short* Qh  = ws + (size_t)bh * (2048 * 64);
  const unsigned short* Kh  = ws + PART_ELEMS + (size_t)bh * (2048 * 64);
  const unsigned short* VTh = ws + 2 * PART_ELEMS + (size_t)bh * (64 * 2048);

  const int srow = t >> 2;
  const int scol = (t & 3) * 16;

  s16x8 qf[2][2];
  {
    const unsigned short* qb = Qh + ((size_t)qt * 128 + w * 32 + lr) * 64 + lkh * 8;
    qf[0][0] = *reinterpret_cast<const s16x8*>(qb);
    qf[0][1] = *reinterpret_cast<const s16x8*>(qb + 32);
    qf[1][0] = *reinterpret_cast<const s16x8*>(qb + 16 * 64);
    qf[1][1] = *reinterpret_cast<const s16x8*>(qb + 16 * 64 + 32);
  }
  {
    const unsigned short* kp = Kh + (size_t)srow * 64 + scol;
    s16x8 k0 = *reinterpret_cast<const s16x8*>(kp);
    s16x8 k1 = *reinterpret_cast<const s16x8*>(kp + 8);
    const unsigned short* vp = VTh + (size_t)srow * 2048 + scol;
    s16x8 v0 = *reinterpret_cast<const s16x8*>(vp);
    s16x8 v1 = *reinterpret_cast<const s16x8*>(vp + 8);
    *reinterpret_cast<s16x8*>(&k_lds[swzs(srow, scol)])      = k0;
    *reinterpret_cast<s16x8*>(&k_lds[swzs(srow, scol + 8)])  = k1;
    *reinterpret_cast<s16x8*>(&vt_lds[swzs(srow, scol)])     = v0;
    *reinterpret_cast<s16x8*>(&vt_lds[swzs(srow, scol + 8)]) = v1;
  }
  __syncthreads();

  f32x4 o_acc[2][4] = {};
  float m_s[2] = {-1e30f, -1e30f};
  float l_s[2] = {0.f, 0.f};

  for (int kt = 0; kt < 32; ++kt) {
    const bool pre = (kt + 1) < 32;

    s16x8 kr0, kr1, vr0, vr1;
    if (pre) {
      const unsigned short* kp = Kh + ((size_t)(kt + 1) * 64 + srow) * 64 + scol;
      kr0 = *reinterpret_cast<const s16x8*>(kp);
      kr1 = *reinterpret_cast<const s16x8*>(kp + 8);
      const unsigned short* vp = VTh + (size_t)srow * 2048 + (kt + 1) * 64 + scol;
      vr0 = *reinterpret_cast<const s16x8*>(vp);
      vr1 = *reinterpret_cast<const s16x8*>(vp + 8);
    }

    f32x4 s_acc[2][4] = {};
    {
      s16x8 kf[4][2];
#pragma unroll
      for (int nt = 0; nt < 4; ++nt) {
        kf[nt][0] = *reinterpret_cast<const s16x8*>(&k_lds[swzs(nt * 16 + lr, lkh * 8)]);
        kf[nt][1] = *reinterpret_cast<const s16x8*>(&k_lds[swzs(nt * 16 + lr, 32 + lkh * 8)]);
      }
#pragma unroll
      for (int qh = 0; qh < 2; ++qh)
#pragma unroll
        for (int nt = 0; nt < 4; ++nt) {
          s_acc[qh][nt] = __builtin_amdgcn_mfma_f32_16x16x32_bf16(kf[nt][0], qf[qh][0], s_acc[qh][nt], 0, 0, 0);
          s_acc[qh][nt] = __builtin_amdgcn_mfma_f32_16x16x32_bf16(kf[nt][1], qf[qh][1], s_acc[qh][nt], 0, 0, 0);
        }
    }

#pragma unroll
    for (int qh = 0; qh < 2; ++qh) {
      float mx = fmaxf(
          fmaxf(fmaxf(fmaxf(s_acc[qh][0][0], s_acc[qh][0][1]), fmaxf(s_acc[qh][0][2], s_acc[qh][0][3])),
                fmaxf(fmaxf(s_acc[qh][1][0], s_acc[qh][1][1]), fmaxf(s_acc[qh][1][2], s_acc[qh][1][3]))),
          fmaxf(fmaxf(fmaxf(s_acc[qh][2][0], s_acc[qh][2][1]), fmaxf(s_acc[qh][2][2], s_acc[qh][2][3])),
                fmaxf(fmaxf(s_acc[qh][3][0], s_acc[qh][3][1]), fmaxf(s_acc[qh][3][2], s_acc[qh][3][3]))));
      mx = fmaxf(mx, __shfl_xor(mx, 16));
      mx = fmaxf(mx, __shfl_xor(mx, 32));

      if (__any(mx > m_s[qh] + 8.0f)) {
        const float mnew = fmaxf(m_s[qh], mx);
        const float sc = fexp2(m_s[qh] - mnew);
        m_s[qh] = mnew;
        l_s[qh] *= sc;
#pragma unroll
        for (int r = 0; r < 4; ++r) {
          const float scr = __shfl(sc, 4 * lkh + r);
          o_acc[qh][0][r] *= scr; o_acc[qh][1][r] *= scr;
          o_acc[qh][2][r] *= scr; o_acc[qh][3][r] *= scr;
        }
      }

      float rs = 0.f;
#pragma unroll
      for (int nt = 0; nt < 4; ++nt) {
        float p0 = fexp2(s_acc[qh][nt][0] - m_s[qh]);
        float p1 = fexp2(s_acc[qh][nt][1] - m_s[qh]);
        float p2 = fexp2(s_acc[qh][nt][2] - m_s[qh]);
        float p3 = fexp2(s_acc[qh][nt][3] - m_s[qh]);
        rs += (p0 + p1) + (p2 + p3);
        u32x2 pk;
        pk.x = pack2bf(p0, p1);
        pk.y = pack2bf(p2, p3);
        *reinterpret_cast<u32x2*>(&p_lds[swzs(w * 32 + qh * 16 + lr, nt * 16 + 4 * lkh)]) = pk;
      }
      rs += __shfl_xor(rs, 16);
      rs += __shfl_xor(rs, 32);
      l_s[qh] += rs;
    }

    {
      s16x8 vf[4][2];
#pragma unroll
      for (int nt = 0; nt < 4; ++nt) {
        vf[nt][0] = *reinterpret_cast<const s16x8*>(&vt_lds[swzs(nt * 16 + lr, lkh * 8)]);
        vf[nt][1] = *reinterpret_cast<const s16x8*>(&vt_lds[swzs(nt * 16 + lr, 32 + lkh * 8)]);
      }
#pragma unroll
      for (int qh = 0; qh < 2; ++qh) {
        s16x8 pf0 = *reinterpret_cast<const s16x8*>(&p_lds[swzs(w * 32 + qh * 16 + lr, lkh * 8)]);
        s16x8 pf1 = *reinterpret_cast<const s16x8*>(&p_lds[swzs(w * 32 + qh * 16 + lr, 32 + lkh * 8)]);
#pragma unroll
        for (int nt = 0; nt < 4; ++nt) {
          o_acc[qh][nt] = __builtin_amdgcn_mfma_f32_16x16x32_bf16(pf0, vf[nt][0], o_acc[qh][nt], 0, 0, 0);
          o_acc[qh][nt] = __builtin_amdgcn_mfma_f32_16x16x32_bf16(pf1, vf[nt][1], o_acc[qh][nt], 0, 0, 0);
        }
      }
    }
    __syncthreads();

    if (pre) {
      *reinterpret_cast<s16x8*>(&k_lds[swzs(srow, scol)])      = kr0;
      *reinterpret_cast<s16x8*>(&k_lds[swzs(srow, scol + 8)])  = kr1;
      *reinterpret_cast<s16x8*>(&vt_lds[swzs(srow, scol)])     = vr0;
      *reinterpret_cast<s16x8*>(&vt_lds[swzs(srow, scol + 8)]) = vr1;
    }
    __syncthreads();
  }

#pragma unroll
  for (int qh = 0; qh < 2; ++qh) {
#pragma unroll
    for (int r = 0; r < 4; ++r) {
      const float lv = __shfl(l_s[qh], 4 * lkh + r);
      const float inv = 1.0f / lv;
      const size_t row = (size_t)b * 2048 + qt * 128 + w * 32 + qh * 16 + lkh * 4 + r;
#pragma unroll
      for (int nt = 0; nt < 4; ++nt) {
        vals[row * 1024 + h * 64 + nt * 16 + lr] = f2bf(o_acc[qh][nt][r] * inv);
      }
    }
  }
}

extern "C" void kernel_launch(void* const* d_in, const int* in_sizes, int n_in,
                              void* d_out, int out_size, void* d_ws, size_t ws_size,
                              hipStream_t stream) {
  const float* x     = (const float*)d_in[0];   // [4,2048,1024]
  const float* w_qkv = (const float*)d_in[1];   // [3072,1024]
  const float* b_qkv = (const float*)d_in[2];   // [3072]
  const float* w_o   = (const float*)d_in[3];   // [1024,1024]
  const float* b_o   = (const float*)d_in[4];   // [1024]
  float* out = (float*)d_out;                   // [4,2048,1024] fp32

  unsigned short* xb     = (unsigned short*)d_ws;   // x bf16; later: vals (aliased)
  unsigned short* planes = xb + PART_ELEMS;         // Q | K | VT planes

  cvt_kernel<<<4096, 256, 0, stream>>>(x, xb);                      // x -> bf16
  gemm_a16<true><<<dim3(24, 64), 256, 0, stream>>>(
      xb, w_qkv, b_qkv, planes, 8192, 3072, 1024);                  // qkv + scatter
  attn_kernel<<<dim3(16, 64), 256, 0, stream>>>(planes, xb);        // vals -> xb
  gemm_a16<false><<<dim3(8, 64), 256, 0, stream>>>(
      xb, w_o, b_o, out, 8192, 1024, 1024);                         // out proj
}

// Round 8
// 242.905 us; speedup vs baseline: 1.8226x; 1.0533x over previous
//
#include <hip/hip_runtime.h>
#include <hip/hip_bf16.h>

// MHA fused pipeline: B=4, S=2048, D=1024, H=16, HD=64.
//   k0: x fp32 -> xb bf16 (once)
//   k1: qkv = xb @ w_qkv^T + b_qkv, epilogue SCATTERS to Q[bh][s][64] (pre-scaled
//       by 0.125*log2e), K[bh][s][64], VT[bh][d][s]   (A via global_load_lds)
//   k2: flash attention, 8 waves/block (256 q-rows), XCD-local block map
//   k3: out = vals @ w_o^T + b_o  (same GEMM, fp32 out)
// ws usage: [xb|vals 16.8MB][Q 16.8][K 16.8][VT 16.8] = 67.1 MB total.

typedef __attribute__((ext_vector_type(4))) float f32x4;
typedef __attribute__((ext_vector_type(8))) short s16x8;
typedef __attribute__((ext_vector_type(2))) unsigned u32x2;
typedef __attribute__((ext_vector_type(4))) unsigned u32x4;

constexpr size_t PART_ELEMS = (size_t)8192 * 1024;  // one bf16 plane

__device__ __forceinline__ unsigned short f2bf(float f) {
  __hip_bfloat16 h = __float2bfloat16(f);
  unsigned short u;
  __builtin_memcpy(&u, &h, 2);
  return u;
}
__device__ __forceinline__ unsigned pack2bf(float a, float b) {
  return (unsigned)f2bf(a) | ((unsigned)f2bf(b) << 16);
}
__device__ __forceinline__ float bf2f(unsigned short u) {
  union { unsigned u; float f; } v; v.u = ((unsigned)u) << 16;
  return v.f;
}
__device__ __forceinline__ float fexp2(float x) {
#if __has_builtin(__builtin_amdgcn_exp2f)
  return __builtin_amdgcn_exp2f(x);
#else
  float r; asm("v_exp_f32 %0, %1" : "=v"(r) : "v"(x)); return r;
#endif
}
// async global->LDS, 16B per lane. LDS dest is wave-uniform base + lane*16.
__device__ __forceinline__ void gload_lds16(const void* g, void* l) {
  __builtin_amdgcn_global_load_lds(
      (const __attribute__((address_space(1))) unsigned*)g,
      (__attribute__((address_space(3))) unsigned*)l, 16, 0, 0);
}
// XOR-swizzled short-index into a [rows][64]-short tile (attn LDS).
__device__ __forceinline__ int swzs(int row, int col) {
  return row * 64 + (((col >> 3) ^ (row & 7)) << 3) + (col & 7);
}

// ---- k0: fp32 -> bf16 convert (x only), 8 elems/thread ----
__global__ __launch_bounds__(256) void cvt_kernel(const float* __restrict__ in,
                                                  unsigned short* __restrict__ out) {
  const size_t i = ((size_t)blockIdx.x * 256 + threadIdx.x) * 8;
  f32x4 v0 = *reinterpret_cast<const f32x4*>(in + i);
  f32x4 v1 = *reinterpret_cast<const f32x4*>(in + i + 4);
  u32x4 pk;
  pk.x = pack2bf(v0.x, v0.y); pk.y = pack2bf(v0.z, v0.w);
  pk.z = pack2bf(v1.x, v1.y); pk.w = pack2bf(v1.z, v1.w);
  *reinterpret_cast<u32x4*>(out + i) = pk;
}

// C[M,N] = A[M,K](bf16) @ Bw[N,K](fp32)^T + bias.
// A staged via global_load_lds into linear [128][32]; B reg-staged+converted.
template <bool SCATTER>
__global__ __launch_bounds__(256) void gemm_a16(
    const unsigned short* __restrict__ A, const float* __restrict__ Bw,
    const float* __restrict__ bias, void* __restrict__ Cptr,
    int M, int N, int K) {
  __shared__ short lds_a[128 * 32];
  __shared__ short lds_b[128 * 32];
  const int t = threadIdx.x;
  const int l = t & 63;
  const int w = t >> 6;
  const int bm = blockIdx.y * 128;
  const int bn = blockIdx.x * 128;
  const int wr = (w >> 1) * 64;
  const int wc = (w & 1) * 64;
  const int lr = l & 15;
  const int lk = (l >> 4) * 8;

  f32x4 acc[4][4] = {};

  const int arow = w * 16 + (l >> 2);
  const int acol = (l & 3) * 8;
  short* adst0 = &lds_a[(w * 16) * 32];
  short* adst1 = &lds_a[(64 + w * 16) * 32];

  for (int k0 = 0; k0 < K; k0 += 32) {
    const unsigned short* as = &A[(size_t)(bm + arow) * K + k0 + acol];
    gload_lds16(as, adst0);
    gload_lds16(as + (size_t)64 * K, adst1);
#pragma unroll
    for (int p = 0; p < 2; ++p) {
      const int row = (t >> 2) + p * 64;
      const int col = (t & 3) * 8;
      const float* src = &Bw[(size_t)(bn + row) * K + k0 + col];
      f32x4 v0 = *reinterpret_cast<const f32x4*>(src);
      f32x4 v1 = *reinterpret_cast<const f32x4*>(src + 4);
      u32x4 pk;
      pk.x = pack2bf(v0.x, v0.y); pk.y = pack2bf(v0.z, v0.w);
      pk.z = pack2bf(v1.x, v1.y); pk.w = pack2bf(v1.z, v1.w);
      *reinterpret_cast<u32x4*>(&lds_b[row * 32 + col]) = pk;
    }
    __syncthreads();

    s16x8 af[4], bfr[4];
#pragma unroll
    for (int mt = 0; mt < 4; ++mt)
      af[mt] = *reinterpret_cast<const s16x8*>(&lds_a[(wr + mt * 16 + lr) * 32 + lk]);
#pragma unroll
    for (int nt = 0; nt < 4; ++nt)
      bfr[nt] = *reinterpret_cast<const s16x8*>(&lds_b[(wc + nt * 16 + lr) * 32 + lk]);
#pragma unroll
    for (int mt = 0; mt < 4; ++mt)
#pragma unroll
      for (int nt = 0; nt < 4; ++nt)
        acc[mt][nt] = __builtin_amdgcn_mfma_f32_16x16x32_bf16(af[mt], bfr[nt], acc[mt][nt], 0, 0, 0);
    __syncthreads();
  }

#pragma unroll
  for (int mt = 0; mt < 4; ++mt) {
#pragma unroll
    for (int nt = 0; nt < 4; ++nt) {
#pragma unroll
      for (int r = 0; r < 4; ++r) {
        const int row = bm + wr + mt * 16 + (l >> 4) * 4 + r;
        const int col = bn + wc + nt * 16 + lr;
        const float vv = acc[mt][nt][r] + bias[col];
        if (SCATTER) {
          const int h = col / 192;
          const int rem = col - h * 192;
          const int part = rem >> 6;          // 0=Q 1=K 2=V
          const int d = rem & 63;
          const int s = row & 2047;
          const size_t bh = (size_t)(row >> 11) * 16 + h;
          unsigned short* W = (unsigned short*)Cptr;
          float vvv = vv;
          if (part == 0) vvv *= 0.1803368801f;  // 0.125 * log2e
          size_t off;
          if (part == 2)
            off = 2 * PART_ELEMS + (bh * 64 + d) * 2048 + s;             // VT[bh][d][s]
          else
            off = (size_t)part * PART_ELEMS + (bh * 2048 + s) * 64 + d;  // Q/K[bh][s][d]
          W[off] = f2bf(vvv);
        } else {
          ((float*)Cptr)[(size_t)row * N + col] = vv;
        }
      }
    }
  }
}

// Flash attention over planes Q[bh][s][64] (pre-scaled), K[bh][s][64], VT[bh][d][s].
// 8 waves/block, 256 q-rows (32/wave); KV tile 64 staged once per block
// (1 b128 K + 1 b128 VT per thread). XCD-local flat-grid decode keeps all
// q-blocks of a bh on one XCD (K/VT working set = 4MB = one XCD L2).
// Swapped QK^T, lane-local softmax, defer-max. LDS 48 KB, 2 blk/CU.
__global__ __launch_bounds__(512, 4) void attn_kernel(
    const unsigned short* __restrict__ ws, unsigned short* __restrict__ vals) {
  __shared__ short k_lds[64 * 64];
  __shared__ short vt_lds[64 * 64];
  __shared__ short p_lds[256 * 64];
  const int t = threadIdx.x;
  const int l = t & 63;
  const int w = t >> 6;            // 0..7
  const int lr = l & 15;
  const int lkh = l >> 4;
  // XCD-local decode: blocks with f%8==xcd handle bh in [xcd*8, xcd*8+8)
  const int f = blockIdx.x;        // 0..511
  const int xcd = f & 7;
  const int j = f >> 3;            // 0..63
  const int bh = xcd * 8 + (j & 7);
  const int qt = j >> 3;           // 0..7
  const int b = bh >> 4;
  const int h = bh & 15;
  const unsigned short* Qh  = ws + (size_t)bh * (2048 * 64);
  const unsigned short* Kh  = ws + PART_ELEMS + (size_t)bh * (2048 * 64);
  const unsigned short* VTh = ws + 2 * PART_ELEMS + (size_t)bh * (64 * 2048);

  const int srow = t >> 3;         // 0..63
  const int scol = (t & 7) * 8;    // 0..56

  // ---- Q fragments straight from global (already scaled by 0.125*log2e) ----
  s16x8 qf[2][2];
  {
    const unsigned short* qb = Qh + ((size_t)qt * 256 + w * 32 + lr) * 64 + lkh * 8;
    qf[0][0] = *reinterpret_cast<const s16x8*>(qb);
    qf[0][1] = *reinterpret_cast<const s16x8*>(qb + 32);
    qf[1][0] = *reinterpret_cast<const s16x8*>(qb + 16 * 64);
    qf[1][1] = *reinterpret_cast<const s16x8*>(qb + 16 * 64 + 32);
  }
  // ---- stage K/VT tile 0 (one b128 each per thread) ----
  {
    s16x8 k0 = *reinterpret_cast<const s16x8*>(Kh + (size_t)srow * 64 + scol);
    s16x8 v0 = *reinterpret_cast<const s16x8*>(VTh + (size_t)srow * 2048 + scol);
    *reinterpret_cast<s16x8*>(&k_lds[swzs(srow, scol)])  = k0;
    *reinterpret_cast<s16x8*>(&vt_lds[swzs(srow, scol)]) = v0;
  }
  __syncthreads();

  f32x4 o_acc[2][4] = {};
  float m_s[2] = {-1e30f, -1e30f};
  float l_s[2] = {0.f, 0.f};

  for (int kt = 0; kt < 32; ++kt) {
    const bool pre = (kt + 1) < 32;

    // ---- issue next K/VT loads early (hide HBM/L2 latency under compute) ----
    s16x8 kr, vr;
    if (pre) {
      kr = *reinterpret_cast<const s16x8*>(Kh + ((size_t)(kt + 1) * 64 + srow) * 64 + scol);
      vr = *reinterpret_cast<const s16x8*>(VTh + (size_t)srow * 2048 + (kt + 1) * 64 + scol);
    }

    // ---- S^T = K Q^T (swapped); kf shared across both q-halves ----
    f32x4 s_acc[2][4] = {};
    {
      s16x8 kf[4][2];
#pragma unroll
      for (int nt = 0; nt < 4; ++nt) {
        kf[nt][0] = *reinterpret_cast<const s16x8*>(&k_lds[swzs(nt * 16 + lr, lkh * 8)]);
        kf[nt][1] = *reinterpret_cast<const s16x8*>(&k_lds[swzs(nt * 16 + lr, 32 + lkh * 8)]);
      }
#pragma unroll
      for (int qh = 0; qh < 2; ++qh)
#pragma unroll
        for (int nt = 0; nt < 4; ++nt) {
          s_acc[qh][nt] = __builtin_amdgcn_mfma_f32_16x16x32_bf16(kf[nt][0], qf[qh][0], s_acc[qh][nt], 0, 0, 0);
          s_acc[qh][nt] = __builtin_amdgcn_mfma_f32_16x16x32_bf16(kf[nt][1], qf[qh][1], s_acc[qh][nt], 0, 0, 0);
        }
    }

    // ---- softmax per q-half: lane holds S^T[kv=nt*16+4*lkh+r][q=qh*16+lr] ----
#pragma unroll
    for (int qh = 0; qh < 2; ++qh) {
      float mx = fmaxf(
          fmaxf(fmaxf(fmaxf(s_acc[qh][0][0], s_acc[qh][0][1]), fmaxf(s_acc[qh][0][2], s_acc[qh][0][3])),
                fmaxf(fmaxf(s_acc[qh][1][0], s_acc[qh][1][1]), fmaxf(s_acc[qh][1][2], s_acc[qh][1][3]))),
          fmaxf(fmaxf(fmaxf(s_acc[qh][2][0], s_acc[qh][2][1]), fmaxf(s_acc[qh][2][2], s_acc[qh][2][3])),
                fmaxf(fmaxf(s_acc[qh][3][0], s_acc[qh][3][1]), fmaxf(s_acc[qh][3][2], s_acc[qh][3][3]))));
      mx = fmaxf(mx, __shfl_xor(mx, 16));
      mx = fmaxf(mx, __shfl_xor(mx, 32));

      if (__any(mx > m_s[qh] + 8.0f)) {  // defer-max
        const float mnew = fmaxf(m_s[qh], mx);
        const float sc = fexp2(m_s[qh] - mnew);
        m_s[qh] = mnew;
        l_s[qh] *= sc;
#pragma unroll
        for (int r = 0; r < 4; ++r) {
          const float scr = __shfl(sc, 4 * lkh + r);
          o_acc[qh][0][r] *= scr; o_acc[qh][1][r] *= scr;
          o_acc[qh][2][r] *= scr; o_acc[qh][3][r] *= scr;
        }
      }

      float rs = 0.f;
#pragma unroll
      for (int nt = 0; nt < 4; ++nt) {
        float p0 = fexp2(s_acc[qh][nt][0] - m_s[qh]);
        float p1 = fexp2(s_acc[qh][nt][1] - m_s[qh]);
        float p2 = fexp2(s_acc[qh][nt][2] - m_s[qh]);
        float p3 = fexp2(s_acc[qh][nt][3] - m_s[qh]);
        rs += (p0 + p1) + (p2 + p3);
        u32x2 pk;
        pk.x = pack2bf(p0, p1);
        pk.y = pack2bf(p2, p3);
        *reinterpret_cast<u32x2*>(&p_lds[swzs(w * 32 + qh * 16 + lr, nt * 16 + 4 * lkh)]) = pk;
      }
      rs += __shfl_xor(rs, 16);
      rs += __shfl_xor(rs, 32);
      l_s[qh] += rs;
    }

    // ---- O += P @ V; vf shared across both q-halves ----
    {
      s16x8 vf[4][2];
#pragma unroll
      for (int nt = 0; nt < 4; ++nt) {
        vf[nt][0] = *reinterpret_cast<const s16x8*>(&vt_lds[swzs(nt * 16 + lr, lkh * 8)]);
        vf[nt][1] = *reinterpret_cast<const s16x8*>(&vt_lds[swzs(nt * 16 + lr, 32 + lkh * 8)]);
      }
#pragma unroll
      for (int qh = 0; qh < 2; ++qh) {
        s16x8 pf0 = *reinterpret_cast<const s16x8*>(&p_lds[swzs(w * 32 + qh * 16 + lr, lkh * 8)]);
        s16x8 pf1 = *reinterpret_cast<const s16x8*>(&p_lds[swzs(w * 32 + qh * 16 + lr, 32 + lkh * 8)]);
#pragma unroll
        for (int nt = 0; nt < 4; ++nt) {
          o_acc[qh][nt] = __builtin_amdgcn_mfma_f32_16x16x32_bf16(pf0, vf[nt][0], o_acc[qh][nt], 0, 0, 0);
          o_acc[qh][nt] = __builtin_amdgcn_mfma_f32_16x16x32_bf16(pf1, vf[nt][1], o_acc[qh][nt], 0, 0, 0);
        }
      }
    }
    __syncthreads();  // all reads of k_lds/vt_lds done

    // ---- write next tiles ----
    if (pre) {
      *reinterpret_cast<s16x8*>(&k_lds[swzs(srow, scol)])  = kr;
      *reinterpret_cast<s16x8*>(&vt_lds[swzs(srow, scol)]) = vr;
    }
    __syncthreads();
  }

  // ---- epilogue: o_acc[qh][nt][r] = O[q=w*32+qh*16+4*lkh+r][d=nt*16+lr] ----
#pragma unroll
  for (int qh = 0; qh < 2; ++qh) {
#pragma unroll
    for (int r = 0; r < 4; ++r) {
      const float lv = __shfl(l_s[qh], 4 * lkh + r);
      const float inv = 1.0f / lv;
      const size_t row = (size_t)b * 2048 + qt * 256 + w * 32 + qh * 16 + lkh * 4 + r;
#pragma unroll
      for (int nt = 0; nt < 4; ++nt) {
        vals[row * 1024 + h * 64 + nt * 16 + lr] = f2bf(o_acc[qh][nt][r] * inv);
      }
    }
  }
}

extern "C" void kernel_launch(void* const* d_in, const int* in_sizes, int n_in,
                              void* d_out, int out_size, void* d_ws, size_t ws_size,
                              hipStream_t stream) {
  const float* x     = (const float*)d_in[0];   // [4,2048,1024]
  const float* w_qkv = (const float*)d_in[1];   // [3072,1024]
  const float* b_qkv = (const float*)d_in[2];   // [3072]
  const float* w_o   = (const float*)d_in[3];   // [1024,1024]
  const float* b_o   = (const float*)d_in[4];   // [1024]
  float* out = (float*)d_out;                   // [4,2048,1024] fp32

  unsigned short* xb     = (unsigned short*)d_ws;   // x bf16; later: vals (aliased)
  unsigned short* planes = xb + PART_ELEMS;         // Q | K | VT planes

  cvt_kernel<<<4096, 256, 0, stream>>>(x, xb);                      // x -> bf16
  gemm_a16<true><<<dim3(24, 64), 256, 0, stream>>>(
      xb, w_qkv, b_qkv, planes, 8192, 3072, 1024);                  // qkv + scatter
  attn_kernel<<<512, 512, 0, stream>>>(planes, xb);                 // vals -> xb
  gemm_a16<false><<<dim3(8, 64), 256, 0, stream>>>(
      xb, w_o, b_o, out, 8192, 1024, 1024);                         // out proj
}

// Round 9
// 231.250 us; speedup vs baseline: 1.9144x; 1.0504x over previous
//
#include <hip/hip_runtime.h>
#include <hip/hip_bf16.h>

// MHA fused pipeline: B=4, S=2048, D=1024, H=16, HD=64.
//   k0a: x fp32 -> xb bf16;  k0b: w_qkv fp32 -> bf16 (in d_out scratch)
//   k1: qkv = xb @ wqkv_b^T + b_qkv, epilogue SCATTERS to Q[bh][s][64]
//       (pre-scaled by 0.125*log2e), K[bh][s][64], VT[bh][d][s]
//   k2: flash attention, 8 waves/block (256 q-rows), XCD-local block map
//   k0c: w_o fp32 -> bf16 (into dead Q-plane)
//   k3: out = vals @ wo_b^T + b_o  (fp32 out)
// Both GEMMs: A and B staged via global_load_lds (m97 structure).
// ws: [xb|vals 16.8MB][Q|wo_b 16.8][K 16.8][VT 16.8] = 67.1 MB.

typedef __attribute__((ext_vector_type(4))) float f32x4;
typedef __attribute__((ext_vector_type(8))) short s16x8;
typedef __attribute__((ext_vector_type(2))) unsigned u32x2;
typedef __attribute__((ext_vector_type(4))) unsigned u32x4;

constexpr size_t PART_ELEMS = (size_t)8192 * 1024;  // one bf16 plane

__device__ __forceinline__ unsigned short f2bf(float f) {
  __hip_bfloat16 h = __float2bfloat16(f);
  unsigned short u;
  __builtin_memcpy(&u, &h, 2);
  return u;
}
__device__ __forceinline__ unsigned pack2bf(float a, float b) {
  return (unsigned)f2bf(a) | ((unsigned)f2bf(b) << 16);
}
__device__ __forceinline__ float bf2f(unsigned short u) {
  union { unsigned u; float f; } v; v.u = ((unsigned)u) << 16;
  return v.f;
}
__device__ __forceinline__ float fexp2(float x) {
#if __has_builtin(__builtin_amdgcn_exp2f)
  return __builtin_amdgcn_exp2f(x);
#else
  float r; asm("v_exp_f32 %0, %1" : "=v"(r) : "v"(x)); return r;
#endif
}
// async global->LDS, 16B per lane. LDS dest is wave-uniform base + lane*16.
__device__ __forceinline__ void gload_lds16(const void* g, void* l) {
  __builtin_amdgcn_global_load_lds(
      (const __attribute__((address_space(1))) unsigned*)g,
      (__attribute__((address_space(3))) unsigned*)l, 16, 0, 0);
}
// XOR-swizzled short-index into a [rows][64]-short tile (attn LDS).
__device__ __forceinline__ int swzs(int row, int col) {
  return row * 64 + (((col >> 3) ^ (row & 7)) << 3) + (col & 7);
}

// ---- k0: fp32 -> bf16 convert, 8 elems/thread ----
__global__ __launch_bounds__(256) void cvt_kernel(const float* __restrict__ in,
                                                  unsigned short* __restrict__ out) {
  const size_t i = ((size_t)blockIdx.x * 256 + threadIdx.x) * 8;
  f32x4 v0 = *reinterpret_cast<const f32x4*>(in + i);
  f32x4 v1 = *reinterpret_cast<const f32x4*>(in + i + 4);
  u32x4 pk;
  pk.x = pack2bf(v0.x, v0.y); pk.y = pack2bf(v0.z, v0.w);
  pk.z = pack2bf(v1.x, v1.y); pk.w = pack2bf(v1.z, v1.w);
  *reinterpret_cast<u32x4*>(out + i) = pk;
}

// C[M,N] = A[M,K](bf16) @ Bw[N,K](bf16)^T + bias. Both staged via
// global_load_lds into linear [128][32] LDS tiles (m97 structure).
template <bool SCATTER>
__global__ __launch_bounds__(256) void gemm_bb(
    const unsigned short* __restrict__ A, const unsigned short* __restrict__ Bw,
    const float* __restrict__ bias, void* __restrict__ Cptr,
    int M, int N, int K) {
  __shared__ short lds_a[128 * 32];
  __shared__ short lds_b[128 * 32];
  const int t = threadIdx.x;
  const int l = t & 63;
  const int w = t >> 6;
  const int bm = blockIdx.y * 128;
  const int bn = blockIdx.x * 128;
  const int wr = (w >> 1) * 64;
  const int wc = (w & 1) * 64;
  const int lr = l & 15;
  const int lk = (l >> 4) * 8;

  f32x4 acc[4][4] = {};

  // staging: wave w covers rows [w*16, w*16+16) and [64+w*16, ...) of each tile
  const int srow = w * 16 + (l >> 2);
  const int scol = (l & 3) * 8;
  short* adst0 = &lds_a[(w * 16) * 32];
  short* adst1 = &lds_a[(64 + w * 16) * 32];
  short* bdst0 = &lds_b[(w * 16) * 32];
  short* bdst1 = &lds_b[(64 + w * 16) * 32];

  for (int k0 = 0; k0 < K; k0 += 32) {
    const unsigned short* as = &A[(size_t)(bm + srow) * K + k0 + scol];
    gload_lds16(as, adst0);
    gload_lds16(as + (size_t)64 * K, adst1);
    const unsigned short* bs = &Bw[(size_t)(bn + srow) * K + k0 + scol];
    gload_lds16(bs, bdst0);
    gload_lds16(bs + (size_t)64 * K, bdst1);
    __syncthreads();

    s16x8 af[4], bfr[4];
#pragma unroll
    for (int mt = 0; mt < 4; ++mt)
      af[mt] = *reinterpret_cast<const s16x8*>(&lds_a[(wr + mt * 16 + lr) * 32 + lk]);
#pragma unroll
    for (int nt = 0; nt < 4; ++nt)
      bfr[nt] = *reinterpret_cast<const s16x8*>(&lds_b[(wc + nt * 16 + lr) * 32 + lk]);
#pragma unroll
    for (int mt = 0; mt < 4; ++mt)
#pragma unroll
      for (int nt = 0; nt < 4; ++nt)
        acc[mt][nt] = __builtin_amdgcn_mfma_f32_16x16x32_bf16(af[mt], bfr[nt], acc[mt][nt], 0, 0, 0);
    __syncthreads();
  }

#pragma unroll
  for (int mt = 0; mt < 4; ++mt) {
#pragma unroll
    for (int nt = 0; nt < 4; ++nt) {
#pragma unroll
      for (int r = 0; r < 4; ++r) {
        const int row = bm + wr + mt * 16 + (l >> 4) * 4 + r;
        const int col = bn + wc + nt * 16 + lr;
        const float vv = acc[mt][nt][r] + bias[col];
        if (SCATTER) {
          const int h = col / 192;
          const int rem = col - h * 192;
          const int part = rem >> 6;          // 0=Q 1=K 2=V
          const int d = rem & 63;
          const int s = row & 2047;
          const size_t bh = (size_t)(row >> 11) * 16 + h;
          unsigned short* W = (unsigned short*)Cptr;
          float vvv = vv;
          if (part == 0) vvv *= 0.1803368801f;  // 0.125 * log2e
          size_t off;
          if (part == 2)
            off = 2 * PART_ELEMS + (bh * 64 + d) * 2048 + s;             // VT[bh][d][s]
          else
            off = (size_t)part * PART_ELEMS + (bh * 2048 + s) * 64 + d;  // Q/K[bh][s][d]
          W[off] = f2bf(vvv);
        } else {
          ((float*)Cptr)[(size_t)row * N + col] = vv;
        }
      }
    }
  }
}

// Flash attention over planes Q[bh][s][64] (pre-scaled), K[bh][s][64], VT[bh][d][s].
// 8 waves/block, 256 q-rows (32/wave); KV tile 64. XCD-local flat-grid decode.
// Swapped QK^T, lane-local softmax, defer-max. LDS 48 KB.
__global__ __launch_bounds__(512, 4) void attn_kernel(
    const unsigned short* __restrict__ ws, unsigned short* __restrict__ vals) {
  __shared__ short k_lds[64 * 64];
  __shared__ short vt_lds[64 * 64];
  __shared__ short p_lds[256 * 64];
  const int t = threadIdx.x;
  const int l = t & 63;
  const int w = t >> 6;            // 0..7
  const int lr = l & 15;
  const int lkh = l >> 4;
  const int f = blockIdx.x;        // 0..511
  const int xcd = f & 7;
  const int j = f >> 3;            // 0..63
  const int bh = xcd * 8 + (j & 7);
  const int qt = j >> 3;           // 0..7
  const int b = bh >> 4;
  const int h = bh & 15;
  const unsigned short* Qh  = ws + (size_t)bh * (2048 * 64);
  const unsigned short* Kh  = ws + PART_ELEMS + (size_t)bh * (2048 * 64);
  const unsigned short* VTh = ws + 2 * PART_ELEMS + (size_t)bh * (64 * 2048);

  const int srow = t >> 3;         // 0..63
  const int scol = (t & 7) * 8;    // 0..56

  s16x8 qf[2][2];
  {
    const unsigned short* qb = Qh + ((size_t)qt * 256 + w * 32 + lr) * 64 + lkh * 8;
    qf[0][0] = *reinterpret_cast<const s16x8*>(qb);
    qf[0][1] = *reinterpret_cast<const s16x8*>(qb + 32);
    qf[1][0] = *reinterpret_cast<const s16x8*>(qb + 16 * 64);
    qf[1][1] = *reinterpret_cast<const s16x8*>(qb + 16 * 64 + 32);
  }
  {
    s16x8 k0 = *reinterpret_cast<const s16x8*>(Kh + (size_t)srow * 64 + scol);
    s16x8 v0 = *reinterpret_cast<const s16x8*>(VTh + (size_t)srow * 2048 + scol);
    *reinterpret_cast<s16x8*>(&k_lds[swzs(srow, scol)])  = k0;
    *reinterpret_cast<s16x8*>(&vt_lds[swzs(srow, scol)]) = v0;
  }
  __syncthreads();

  f32x4 o_acc[2][4] = {};
  float m_s[2] = {-1e30f, -1e30f};
  float l_s[2] = {0.f, 0.f};

  for (int kt = 0; kt < 32; ++kt) {
    const bool pre = (kt + 1) < 32;

    s16x8 kr, vr;
    if (pre) {
      kr = *reinterpret_cast<const s16x8*>(Kh + ((size_t)(kt + 1) * 64 + srow) * 64 + scol);
      vr = *reinterpret_cast<const s16x8*>(VTh + (size_t)srow * 2048 + (kt + 1) * 64 + scol);
    }

    f32x4 s_acc[2][4] = {};
    {
      s16x8 kf[4][2];
#pragma unroll
      for (int nt = 0; nt < 4; ++nt) {
        kf[nt][0] = *reinterpret_cast<const s16x8*>(&k_lds[swzs(nt * 16 + lr, lkh * 8)]);
        kf[nt][1] = *reinterpret_cast<const s16x8*>(&k_lds[swzs(nt * 16 + lr, 32 + lkh * 8)]);
      }
#pragma unroll
      for (int qh = 0; qh < 2; ++qh)
#pragma unroll
        for (int nt = 0; nt < 4; ++nt) {
          s_acc[qh][nt] = __builtin_amdgcn_mfma_f32_16x16x32_bf16(kf[nt][0], qf[qh][0], s_acc[qh][nt], 0, 0, 0);
          s_acc[qh][nt] = __builtin_amdgcn_mfma_f32_16x16x32_bf16(kf[nt][1], qf[qh][1], s_acc[qh][nt], 0, 0, 0);
        }
    }

#pragma unroll
    for (int qh = 0; qh < 2; ++qh) {
      float mx = fmaxf(
          fmaxf(fmaxf(fmaxf(s_acc[qh][0][0], s_acc[qh][0][1]), fmaxf(s_acc[qh][0][2], s_acc[qh][0][3])),
                fmaxf(fmaxf(s_acc[qh][1][0], s_acc[qh][1][1]), fmaxf(s_acc[qh][1][2], s_acc[qh][1][3]))),
          fmaxf(fmaxf(fmaxf(s_acc[qh][2][0], s_acc[qh][2][1]), fmaxf(s_acc[qh][2][2], s_acc[qh][2][3])),
                fmaxf(fmaxf(s_acc[qh][3][0], s_acc[qh][3][1]), fmaxf(s_acc[qh][3][2], s_acc[qh][3][3]))));
      mx = fmaxf(mx, __shfl_xor(mx, 16));
      mx = fmaxf(mx, __shfl_xor(mx, 32));

      if (__any(mx > m_s[qh] + 8.0f)) {
        const float mnew = fmaxf(m_s[qh], mx);
        const float sc = fexp2(m_s[qh] - mnew);
        m_s[qh] = mnew;
        l_s[qh] *= sc;
#pragma unroll
        for (int r = 0; r < 4; ++r) {
          const float scr = __shfl(sc, 4 * lkh + r);
          o_acc[qh][0][r] *= scr; o_acc[qh][1][r] *= scr;
          o_acc[qh][2][r] *= scr; o_acc[qh][3][r] *= scr;
        }
      }

      float rs = 0.f;
#pragma unroll
      for (int nt = 0; nt < 4; ++nt) {
        float p0 = fexp2(s_acc[qh][nt][0] - m_s[qh]);
        float p1 = fexp2(s_acc[qh][nt][1] - m_s[qh]);
        float p2 = fexp2(s_acc[qh][nt][2] - m_s[qh]);
        float p3 = fexp2(s_acc[qh][nt][3] - m_s[qh]);
        rs += (p0 + p1) + (p2 + p3);
        u32x2 pk;
        pk.x = pack2bf(p0, p1);
        pk.y = pack2bf(p2, p3);
        *reinterpret_cast<u32x2*>(&p_lds[swzs(w * 32 + qh * 16 + lr, nt * 16 + 4 * lkh)]) = pk;
      }
      rs += __shfl_xor(rs, 16);
      rs += __shfl_xor(rs, 32);
      l_s[qh] += rs;
    }

    {
      s16x8 vf[4][2];
#pragma unroll
      for (int nt = 0; nt < 4; ++nt) {
        vf[nt][0] = *reinterpret_cast<const s16x8*>(&vt_lds[swzs(nt * 16 + lr, lkh * 8)]);
        vf[nt][1] = *reinterpret_cast<const s16x8*>(&vt_lds[swzs(nt * 16 + lr, 32 + lkh * 8)]);
      }
#pragma unroll
      for (int qh = 0; qh < 2; ++qh) {
        s16x8 pf0 = *reinterpret_cast<const s16x8*>(&p_lds[swzs(w * 32 + qh * 16 + lr, lkh * 8)]);
        s16x8 pf1 = *reinterpret_cast<const s16x8*>(&p_lds[swzs(w * 32 + qh * 16 + lr, 32 + lkh * 8)]);
#pragma unroll
        for (int nt = 0; nt < 4; ++nt) {
          o_acc[qh][nt] = __builtin_amdgcn_mfma_f32_16x16x32_bf16(pf0, vf[nt][0], o_acc[qh][nt], 0, 0, 0);
          o_acc[qh][nt] = __builtin_amdgcn_mfma_f32_16x16x32_bf16(pf1, vf[nt][1], o_acc[qh][nt], 0, 0, 0);
        }
      }
    }
    __syncthreads();

    if (pre) {
      *reinterpret_cast<s16x8*>(&k_lds[swzs(srow, scol)])  = kr;
      *reinterpret_cast<s16x8*>(&vt_lds[swzs(srow, scol)]) = vr;
    }
    __syncthreads();
  }

#pragma unroll
  for (int qh = 0; qh < 2; ++qh) {
#pragma unroll
    for (int r = 0; r < 4; ++r) {
      const float lv = __shfl(l_s[qh], 4 * lkh + r);
      const float inv = 1.0f / lv;
      const size_t row = (size_t)b * 2048 + qt * 256 + w * 32 + qh * 16 + lkh * 4 + r;
#pragma unroll
      for (int nt = 0; nt < 4; ++nt) {
        vals[row * 1024 + h * 64 + nt * 16 + lr] = f2bf(o_acc[qh][nt][r] * inv);
      }
    }
  }
}

extern "C" void kernel_launch(void* const* d_in, const int* in_sizes, int n_in,
                              void* d_out, int out_size, void* d_ws, size_t ws_size,
                              hipStream_t stream) {
  const float* x     = (const float*)d_in[0];   // [4,2048,1024]
  const float* w_qkv = (const float*)d_in[1];   // [3072,1024]
  const float* b_qkv = (const float*)d_in[2];   // [3072]
  const float* w_o   = (const float*)d_in[3];   // [1024,1024]
  const float* b_o   = (const float*)d_in[4];   // [1024]
  float* out = (float*)d_out;                   // [4,2048,1024] fp32

  unsigned short* xb     = (unsigned short*)d_ws;   // x bf16; later: vals (aliased)
  unsigned short* planes = xb + PART_ELEMS;         // Q | K | VT planes
  unsigned short* wqkv_b = (unsigned short*)d_out;  // d_out as scratch (6.3 MB),
                                                    // fully overwritten by gemm3
  unsigned short* wo_b   = planes;                  // Q-plane, dead after attn

  cvt_kernel<<<4096, 256, 0, stream>>>(x, xb);                      // x -> bf16
  cvt_kernel<<<1536, 256, 0, stream>>>(w_qkv, wqkv_b);              // w_qkv -> bf16
  gemm_bb<true><<<dim3(24, 64), 256, 0, stream>>>(
      xb, wqkv_b, b_qkv, planes, 8192, 3072, 1024);                 // qkv + scatter
  attn_kernel<<<512, 512, 0, stream>>>(planes, xb);                 // vals -> xb
  cvt_kernel<<<512, 256, 0, stream>>>(w_o, wo_b);                   // w_o -> bf16
  gemm_bb<false><<<dim3(8, 64), 256, 0, stream>>>(
      xb, wo_b, b_o, out, 8192, 1024, 1024);                        // out proj
}

// Round 11
// 225.109 us; speedup vs baseline: 1.9667x; 1.0273x over previous
//
#include <hip/hip_runtime.h>
#include <hip/hip_bf16.h>

// MHA fused pipeline: B=4, S=2048, D=1024, H=16, HD=64.
//   k0: x, w_qkv fp32 -> bf16 (w_qkv into d_out scratch; gemm3 overwrites later)
//   k1: qkv = xb @ wqkv_b^T + b_qkv, epilogue SCATTERS to Q[bh][s][64]
//       (pre-scaled by 0.125*log2e), K[bh][s][64], VT[bh][d][s]
//   k2: flash attention, 8 waves/block, XCD-local map, dbuf K/VT, 1 barrier/kt
//   k0c: w_o -> bf16 into Q-plane (dead after attn)  [NOT d_out: gemm3 reads it
//        while writing d_out -> race. R10 bug.]
//   k3: out = vals @ wo_b^T + b_o  (fp32 out)
// Both GEMMs: A/B via global_load_lds (m97 structure) + XCD bm-chunked grid.
// ws: [xb|vals 16.8MB][Q|wo_b 16.8][K 16.8][VT 16.8] = 67.1 MB.

typedef __attribute__((ext_vector_type(4))) float f32x4;
typedef __attribute__((ext_vector_type(8))) short s16x8;
typedef __attribute__((ext_vector_type(2))) unsigned u32x2;
typedef __attribute__((ext_vector_type(4))) unsigned u32x4;

constexpr size_t PART_ELEMS = (size_t)8192 * 1024;  // one bf16 plane

__device__ __forceinline__ unsigned short f2bf(float f) {
  __hip_bfloat16 h = __float2bfloat16(f);
  unsigned short u;
  __builtin_memcpy(&u, &h, 2);
  return u;
}
__device__ __forceinline__ unsigned pack2bf(float a, float b) {
  return (unsigned)f2bf(a) | ((unsigned)f2bf(b) << 16);
}
__device__ __forceinline__ float bf2f(unsigned short u) {
  union { unsigned u; float f; } v; v.u = ((unsigned)u) << 16;
  return v.f;
}
__device__ __forceinline__ float fexp2(float x) {
#if __has_builtin(__builtin_amdgcn_exp2f)
  return __builtin_amdgcn_exp2f(x);
#else
  float r; asm("v_exp_f32 %0, %1" : "=v"(r) : "v"(x)); return r;
#endif
}
__device__ __forceinline__ float max3f(float a, float b, float c) {
  return fmaxf(fmaxf(a, b), c);  // clang fuses to v_max3_f32
}
// async global->LDS, 16B per lane. LDS dest is wave-uniform base + lane*16.
__device__ __forceinline__ void gload_lds16(const void* g, void* l) {
  __builtin_amdgcn_global_load_lds(
      (const __attribute__((address_space(1))) unsigned*)g,
      (__attribute__((address_space(3))) unsigned*)l, 16, 0, 0);
}
// XOR-swizzled short-index into a [rows][64]-short tile (attn LDS).
__device__ __forceinline__ int swzs(int row, int col) {
  return row * 64 + (((col >> 3) ^ (row & 7)) << 3) + (col & 7);
}

// ---- k0: fp32 -> bf16 convert, 8 elems/thread ----
__global__ __launch_bounds__(256) void cvt_kernel(const float* __restrict__ in,
                                                  unsigned short* __restrict__ out) {
  const size_t i = ((size_t)blockIdx.x * 256 + threadIdx.x) * 8;
  f32x4 v0 = *reinterpret_cast<const f32x4*>(in + i);
  f32x4 v1 = *reinterpret_cast<const f32x4*>(in + i + 4);
  u32x4 pk;
  pk.x = pack2bf(v0.x, v0.y); pk.y = pack2bf(v0.z, v0.w);
  pk.z = pack2bf(v1.x, v1.y); pk.w = pack2bf(v1.z, v1.w);
  *reinterpret_cast<u32x4*>(out + i) = pk;
}

// C[M,N] = A[M,K](bf16) @ Bw[N,K](bf16)^T + bias. Both staged via
// global_load_lds into linear [128][32] LDS tiles (m97 structure).
// Flat grid, XCD bm-chunked: XCD c owns bm tiles [c*8, c*8+8) x all bn.
template <bool SCATTER>
__global__ __launch_bounds__(256) void gemm_bb(
    const unsigned short* __restrict__ A, const unsigned short* __restrict__ Bw,
    const float* __restrict__ bias, void* __restrict__ Cptr,
    int M, int N, int K) {
  __shared__ short lds_a[128 * 32];
  __shared__ short lds_b[128 * 32];
  const int t = threadIdx.x;
  const int l = t & 63;
  const int w = t >> 6;
  const int id = blockIdx.x;
  const int xcd = id & 7;
  const int rr = id >> 3;
  const int bm = (xcd * 8 + (rr & 7)) * 128;
  const int bn = (rr >> 3) * 128;
  const int wr = (w >> 1) * 64;
  const int wc = (w & 1) * 64;
  const int lr = l & 15;
  const int lk = (l >> 4) * 8;

  f32x4 acc[4][4] = {};

  const int srow = w * 16 + (l >> 2);
  const int scol = (l & 3) * 8;
  short* adst0 = &lds_a[(w * 16) * 32];
  short* adst1 = &lds_a[(64 + w * 16) * 32];
  short* bdst0 = &lds_b[(w * 16) * 32];
  short* bdst1 = &lds_b[(64 + w * 16) * 32];

  for (int k0 = 0; k0 < K; k0 += 32) {
    const unsigned short* as = &A[(size_t)(bm + srow) * K + k0 + scol];
    gload_lds16(as, adst0);
    gload_lds16(as + (size_t)64 * K, adst1);
    const unsigned short* bs = &Bw[(size_t)(bn + srow) * K + k0 + scol];
    gload_lds16(bs, bdst0);
    gload_lds16(bs + (size_t)64 * K, bdst1);
    __syncthreads();

    s16x8 af[4], bfr[4];
#pragma unroll
    for (int mt = 0; mt < 4; ++mt)
      af[mt] = *reinterpret_cast<const s16x8*>(&lds_a[(wr + mt * 16 + lr) * 32 + lk]);
#pragma unroll
    for (int nt = 0; nt < 4; ++nt)
      bfr[nt] = *reinterpret_cast<const s16x8*>(&lds_b[(wc + nt * 16 + lr) * 32 + lk]);
#pragma unroll
    for (int mt = 0; mt < 4; ++mt)
#pragma unroll
      for (int nt = 0; nt < 4; ++nt)
        acc[mt][nt] = __builtin_amdgcn_mfma_f32_16x16x32_bf16(af[mt], bfr[nt], acc[mt][nt], 0, 0, 0);
    __syncthreads();
  }

#pragma unroll
  for (int mt = 0; mt < 4; ++mt) {
#pragma unroll
    for (int nt = 0; nt < 4; ++nt) {
#pragma unroll
      for (int r = 0; r < 4; ++r) {
        const int row = bm + wr + mt * 16 + (l >> 4) * 4 + r;
        const int col = bn + wc + nt * 16 + lr;
        const float vv = acc[mt][nt][r] + bias[col];
        if (SCATTER) {
          const int h = col / 192;
          const int rem = col - h * 192;
          const int part = rem >> 6;          // 0=Q 1=K 2=V
          const int d = rem & 63;
          const int s = row & 2047;
          const size_t bh = (size_t)(row >> 11) * 16 + h;
          unsigned short* W = (unsigned short*)Cptr;
          float vvv = vv;
          if (part == 0) vvv *= 0.1803368801f;  // 0.125 * log2e
          size_t off;
          if (part == 2)
            off = 2 * PART_ELEMS + (bh * 64 + d) * 2048 + s;             // VT[bh][d][s]
          else
            off = (size_t)part * PART_ELEMS + (bh * 2048 + s) * 64 + d;  // Q/K[bh][s][d]
          W[off] = f2bf(vvv);
        } else {
          ((float*)Cptr)[(size_t)row * N + col] = vv;
        }
      }
    }
  }
}

// Flash attention over planes Q[bh][s][64] (pre-scaled), K[bh][s][64], VT[bh][d][s].
// 8 waves/block, 256 q-rows (32/wave); KV tile 64, double-buffered, ONE barrier
// per kt (reads of buf cur finish before the end-of-iter barrier; writes to cur
// only occur next iter after it). XCD-local flat-grid decode. Swapped QK^T,
// lane-local softmax, deferred l-reduction, defer-max, setprio. LDS 64 KB.
__global__ __launch_bounds__(512, 4) void attn_kernel(
    const unsigned short* __restrict__ ws, unsigned short* __restrict__ vals) {
  __shared__ short k_lds[2][64 * 64];
  __shared__ short vt_lds[2][64 * 64];
  __shared__ short p_lds[256 * 64];
  const int t = threadIdx.x;
  const int l = t & 63;
  const int w = t >> 6;            // 0..7
  const int lr = l & 15;
  const int lkh = l >> 4;
  const int f = blockIdx.x;        // 0..511
  const int xcd = f & 7;
  const int j = f >> 3;            // 0..63
  const int bh = xcd * 8 + (j & 7);
  const int qt = j >> 3;           // 0..7
  const int b = bh >> 4;
  const int h = bh & 15;
  const unsigned short* Qh  = ws + (size_t)bh * (2048 * 64);
  const unsigned short* Kh  = ws + PART_ELEMS + (size_t)bh * (2048 * 64);
  const unsigned short* VTh = ws + 2 * PART_ELEMS + (size_t)bh * (64 * 2048);

  const int srow = t >> 3;         // 0..63
  const int scol = (t & 7) * 8;    // 0..56

  s16x8 qf[2][2];
  {
    const unsigned short* qb = Qh + ((size_t)qt * 256 + w * 32 + lr) * 64 + lkh * 8;
    qf[0][0] = *reinterpret_cast<const s16x8*>(qb);
    qf[0][1] = *reinterpret_cast<const s16x8*>(qb + 32);
    qf[1][0] = *reinterpret_cast<const s16x8*>(qb + 16 * 64);
    qf[1][1] = *reinterpret_cast<const s16x8*>(qb + 16 * 64 + 32);
  }
  {
    s16x8 k0 = *reinterpret_cast<const s16x8*>(Kh + (size_t)srow * 64 + scol);
    s16x8 v0 = *reinterpret_cast<const s16x8*>(VTh + (size_t)srow * 2048 + scol);
    *reinterpret_cast<s16x8*>(&k_lds[0][swzs(srow, scol)])  = k0;
    *reinterpret_cast<s16x8*>(&vt_lds[0][swzs(srow, scol)]) = v0;
  }
  __syncthreads();

  f32x4 o_acc[2][4] = {};
  float m_s[2] = {-1e30f, -1e30f};
  float l_s[2] = {0.f, 0.f};       // lane-local partial (deferred reduction)

  for (int kt = 0; kt < 32; ++kt) {
    const int cur = kt & 1;
    const int nxt = cur ^ 1;
    const bool pre = (kt + 1) < 32;

    s16x8 kr, vr;
    if (pre) {
      kr = *reinterpret_cast<const s16x8*>(Kh + ((size_t)(kt + 1) * 64 + srow) * 64 + scol);
      vr = *reinterpret_cast<const s16x8*>(VTh + (size_t)srow * 2048 + (kt + 1) * 64 + scol);
    }

    // ---- S^T = K Q^T (swapped); kf shared across both q-halves ----
    f32x4 s_acc[2][4] = {};
    {
      s16x8 kf[4][2];
#pragma unroll
      for (int nt = 0; nt < 4; ++nt) {
        kf[nt][0] = *reinterpret_cast<const s16x8*>(&k_lds[cur][swzs(nt * 16 + lr, lkh * 8)]);
        kf[nt][1] = *reinterpret_cast<const s16x8*>(&k_lds[cur][swzs(nt * 16 + lr, 32 + lkh * 8)]);
      }
      __builtin_amdgcn_s_setprio(1);
#pragma unroll
      for (int qh = 0; qh < 2; ++qh)
#pragma unroll
        for (int nt = 0; nt < 4; ++nt) {
          s_acc[qh][nt] = __builtin_amdgcn_mfma_f32_16x16x32_bf16(kf[nt][0], qf[qh][0], s_acc[qh][nt], 0, 0, 0);
          s_acc[qh][nt] = __builtin_amdgcn_mfma_f32_16x16x32_bf16(kf[nt][1], qf[qh][1], s_acc[qh][nt], 0, 0, 0);
        }
      __builtin_amdgcn_s_setprio(0);
    }

    // ---- softmax per q-half: lane holds S^T[kv=nt*16+4*lkh+r][q=lr] ----
#pragma unroll
    for (int qh = 0; qh < 2; ++qh) {
      float mx = max3f(max3f(s_acc[qh][0][0], s_acc[qh][0][1], s_acc[qh][0][2]),
                       max3f(s_acc[qh][0][3], s_acc[qh][1][0], s_acc[qh][1][1]),
                       max3f(s_acc[qh][1][2], s_acc[qh][1][3], s_acc[qh][2][0]));
      mx = max3f(mx,
                 max3f(s_acc[qh][2][1], s_acc[qh][2][2], s_acc[qh][2][3]),
                 max3f(s_acc[qh][3][0], s_acc[qh][3][1], s_acc[qh][3][2]));
      mx = fmaxf(mx, s_acc[qh][3][3]);
      mx = fmaxf(mx, __shfl_xor(mx, 16));
      mx = fmaxf(mx, __shfl_xor(mx, 32));

      if (__any(mx > m_s[qh] + 8.0f)) {  // defer-max
        const float mnew = fmaxf(m_s[qh], mx);
        const float sc = fexp2(m_s[qh] - mnew);
        m_s[qh] = mnew;
        l_s[qh] *= sc;                   // lane-local partial: sc row-uniform
#pragma unroll
        for (int r = 0; r < 4; ++r) {
          const float scr = __shfl(sc, 4 * lkh + r);
          o_acc[qh][0][r] *= scr; o_acc[qh][1][r] *= scr;
          o_acc[qh][2][r] *= scr; o_acc[qh][3][r] *= scr;
        }
      }

      float rs = 0.f;
#pragma unroll
      for (int nt = 0; nt < 4; ++nt) {
        float p0 = fexp2(s_acc[qh][nt][0] - m_s[qh]);
        float p1 = fexp2(s_acc[qh][nt][1] - m_s[qh]);
        float p2 = fexp2(s_acc[qh][nt][2] - m_s[qh]);
        float p3 = fexp2(s_acc[qh][nt][3] - m_s[qh]);
        rs += (p0 + p1) + (p2 + p3);
        u32x2 pk;
        pk.x = pack2bf(p0, p1);
        pk.y = pack2bf(p2, p3);
        *reinterpret_cast<u32x2*>(&p_lds[swzs(w * 32 + qh * 16 + lr, nt * 16 + 4 * lkh)]) = pk;
      }
      l_s[qh] += rs;                     // no per-kt cross-lane reduce
    }

    // ---- O += P @ V; vf shared across both q-halves ----
    {
      s16x8 vf[4][2];
#pragma unroll
      for (int nt = 0; nt < 4; ++nt) {
        vf[nt][0] = *reinterpret_cast<const s16x8*>(&vt_lds[cur][swzs(nt * 16 + lr, lkh * 8)]);
        vf[nt][1] = *reinterpret_cast<const s16x8*>(&vt_lds[cur][swzs(nt * 16 + lr, 32 + lkh * 8)]);
      }
      __builtin_amdgcn_s_setprio(1);
#pragma unroll
      for (int qh = 0; qh < 2; ++qh) {
        s16x8 pf0 = *reinterpret_cast<const s16x8*>(&p_lds[swzs(w * 32 + qh * 16 + lr, lkh * 8)]);
        s16x8 pf1 = *reinterpret_cast<const s16x8*>(&p_lds[swzs(w * 32 + qh * 16 + lr, 32 + lkh * 8)]);
#pragma unroll
        for (int nt = 0; nt < 4; ++nt) {
          o_acc[qh][nt] = __builtin_amdgcn_mfma_f32_16x16x32_bf16(pf0, vf[nt][0], o_acc[qh][nt], 0, 0, 0);
          o_acc[qh][nt] = __builtin_amdgcn_mfma_f32_16x16x32_bf16(pf1, vf[nt][1], o_acc[qh][nt], 0, 0, 0);
        }
      }
      __builtin_amdgcn_s_setprio(0);
    }

    // ---- write next tiles into the other buffer; ONE barrier per kt ----
    if (pre) {
      *reinterpret_cast<s16x8*>(&k_lds[nxt][swzs(srow, scol)])  = kr;
      *reinterpret_cast<s16x8*>(&vt_lds[nxt][swzs(srow, scol)]) = vr;
    }
    __syncthreads();
  }

  // ---- deferred l reduction, then epilogue ----
#pragma unroll
  for (int qh = 0; qh < 2; ++qh) {
    l_s[qh] += __shfl_xor(l_s[qh], 16);
    l_s[qh] += __shfl_xor(l_s[qh], 32);
  }
#pragma unroll
  for (int qh = 0; qh < 2; ++qh) {
#pragma unroll
    for (int r = 0; r < 4; ++r) {
      const float lv = __shfl(l_s[qh], 4 * lkh + r);
      const float inv = 1.0f / lv;
      const size_t row = (size_t)b * 2048 + qt * 256 + w * 32 + qh * 16 + lkh * 4 + r;
#pragma unroll
      for (int nt = 0; nt < 4; ++nt) {
        vals[row * 1024 + h * 64 + nt * 16 + lr] = f2bf(o_acc[qh][nt][r] * inv);
      }
    }
  }
}

extern "C" void kernel_launch(void* const* d_in, const int* in_sizes, int n_in,
                              void* d_out, int out_size, void* d_ws, size_t ws_size,
                              hipStream_t stream) {
  const float* x     = (const float*)d_in[0];   // [4,2048,1024]
  const float* w_qkv = (const float*)d_in[1];   // [3072,1024]
  const float* b_qkv = (const float*)d_in[2];   // [3072]
  const float* w_o   = (const float*)d_in[3];   // [1024,1024]
  const float* b_o   = (const float*)d_in[4];   // [1024]
  float* out = (float*)d_out;                   // [4,2048,1024] fp32

  unsigned short* xb     = (unsigned short*)d_ws;   // x bf16; later: vals (aliased)
  unsigned short* planes = xb + PART_ELEMS;         // Q | K | VT planes
  unsigned short* wqkv_b = (unsigned short*)d_out;  // d_out scratch; only read by
                                                    // gemm1 (d_out untouched until gemm3)
  unsigned short* wo_b   = planes;                  // Q-plane, dead after attn

  cvt_kernel<<<4096, 256, 0, stream>>>(x, xb);                      // x -> bf16
  cvt_kernel<<<1536, 256, 0, stream>>>(w_qkv, wqkv_b);              // w_qkv -> bf16
  gemm_bb<true><<<1536, 256, 0, stream>>>(
      xb, wqkv_b, b_qkv, planes, 8192, 3072, 1024);                 // qkv + scatter
  attn_kernel<<<512, 512, 0, stream>>>(planes, xb);                 // vals -> xb
  cvt_kernel<<<512, 256, 0, stream>>>(w_o, wo_b);                   // w_o -> bf16 (Q-plane)
  gemm_bb<false><<<512, 256, 0, stream>>>(
      xb, wo_b, b_o, out, 8192, 1024, 1024);                        // out proj
}